// Round 1
// baseline (2295.950 us; speedup 1.0000x reference)
//
#include <hip/hip_runtime.h>
#include <cstdint>
#include <cstddef>

// ---------------------------------------------------------------------------
// TemperGraph: exact re-implementation of the JAX reference on gfx950.
// R0: correctness-first. fp32 VALU GEMMs (no MFMA: routing argmax needs
// ~1e-5 logit fidelity; bf16 would flip stop decisions).
// PRNG: JAX threefry, PARTITIONABLE convention (modern JAX default).
// Flip JPART to 0 if absmax comes back ~0.4 (legacy convention).
// ---------------------------------------------------------------------------

#define JPART 1

#define NPATCH 32768          // B(2048) * num_patches(16)
#define HID 512
#define NHOP 4

// ------------------------------- threefry ----------------------------------
__device__ __forceinline__ uint32_t rotl32(uint32_t x, int r){ return (x<<r)|(x>>(32-r)); }

__device__ __forceinline__ void tf2x32(uint32_t k0, uint32_t k1, uint32_t x0, uint32_t x1,
                                       uint32_t& o0, uint32_t& o1){
  uint32_t k2 = k0 ^ k1 ^ 0x1BD11BDAu;
  x0 += k0; x1 += k1;
#define TFR(r) { x0 += x1; x1 = rotl32(x1,(r)); x1 ^= x0; }
  TFR(13) TFR(15) TFR(26) TFR(6)   x0 += k1; x1 += k2 + 1u;
  TFR(17) TFR(29) TFR(16) TFR(24)  x0 += k2; x1 += k0 + 2u;
  TFR(13) TFR(15) TFR(26) TFR(6)   x0 += k0; x1 += k1 + 3u;
  TFR(17) TFR(29) TFR(16) TFR(24)  x0 += k1; x1 += k2 + 4u;
  TFR(13) TFR(15) TFR(26) TFR(6)   x0 += k2; x1 += k0 + 5u;
#undef TFR
  o0 = x0; o1 = x1;
}

// random_bits(key, 32, shape) at flat index idx; n = total element count
__device__ __forceinline__ uint32_t jbits32(uint32_t k0, uint32_t k1, uint32_t idx, uint32_t n){
#if JPART
  (void)n;
  uint32_t a, b; tf2x32(k0, k1, 0u, idx, a, b);
  return a ^ b;
#else
  uint32_t h = n >> 1;
  uint32_t a, b;
  if (idx < h) { tf2x32(k0, k1, idx, h + idx, a, b); return a; }
  else         { tf2x32(k0, k1, idx - h, idx, a, b); return b; }
#endif
}

// jax.random.split(key) -> (new_rng, child)
__device__ __forceinline__ void jsplit(uint32_t& r0, uint32_t& r1, uint32_t& c0, uint32_t& c1){
#if JPART
  uint32_t n0, n1;
  tf2x32(r0, r1, 0u, 0u, n0, n1);
  tf2x32(r0, r1, 0u, 1u, c0, c1);
  r0 = n0; r1 = n1;
#else
  uint32_t a0, a1, b0, b1;
  tf2x32(r0, r1, 0u, 2u, a0, a1);
  tf2x32(r0, r1, 1u, 3u, b0, b1);
  r0 = a0; r1 = b0; c0 = a1; c1 = b1;
#endif
}

// gumbel sample from 32 random bits, replicating jax _uniform + _gumbel
__device__ __forceinline__ float jgumbel(uint32_t bits){
  float f = __uint_as_float(0x3f800000u | (bits >> 9)) - 1.0f;
  float u = fmaxf(f, 1.17549435e-38f);
  return -logf(-logf(u));
}

// ------------------------------- key derivation ----------------------------
// keys[0..1]=tk ; per hop h: keys[2+4h..3+4h]=ok_h, keys[4+4h..5+4h]=sk_h
__global__ void k_keys(const int* __restrict__ seed, const float* __restrict__ op_logits,
                       uint32_t* __restrict__ keys, float* __restrict__ logp3){
  if (threadIdx.x != 0 || blockIdx.x != 0) return;
  uint32_t r0 = 0u, r1 = (uint32_t)seed[0];
  uint32_t c0, c1;
  jsplit(r0, r1, c0, c1); keys[0] = c0; keys[1] = c1;          // tk
  for (int h = 0; h < NHOP; h++){
    jsplit(r0, r1, c0, c1); keys[2 + 4*h] = c0; keys[3 + 4*h] = c1;  // ok_h
    jsplit(r0, r1, c0, c1); keys[4 + 4*h] = c0; keys[5 + 4*h] = c1;  // sk_h
  }
  // log(softmax(op_logits)) -- replicate jax.nn.softmax then jnp.log
  float l0 = op_logits[0], l1 = op_logits[1], l2 = op_logits[2];
  float mm = fmaxf(l0, fmaxf(l1, l2));
  float e0 = expf(l0-mm), e1 = expf(l1-mm), e2 = expf(l2-mm);
  float ssum = e0 + e1 + e2;
  logp3[0] = logf(e0/ssum); logp3[1] = logf(e1/ssum); logp3[2] = logf(e2/ssum);
}

// ------------------------------- init --------------------------------------
// patch_tempers = randint(tk,(N,),0,64): span=64 -> lower_bits % 64,
// lower_bits at flat index N+i of a (2,N) draw.
__global__ __launch_bounds__(256)
void k_init(const uint32_t* __restrict__ keys, int* __restrict__ tempers, int* __restrict__ done){
  int i = blockIdx.x*256 + threadIdx.x;
  uint32_t b = jbits32(keys[0], keys[1], (uint32_t)(NPATCH + i), 2u*NPATCH);
  tempers[i] = (int)(b & 63u);
  done[i] = 0;
}

// ------------------------------- precompute --------------------------------
// idW[t][j]  = id_embeds[t] @ W1[512:516, :]
// opWb[o][j] = op_emb[o] @ W1[516:772, :] + b1[j]
// tidWb[t][c]= tid_emb[t] @ Wr1[512:516, :] + br1[c]
__global__ __launch_bounds__(256)
void k_precomp(const float* __restrict__ id_embeds, const float* __restrict__ op_emb,
               const float* __restrict__ tid_emb,
               const float* __restrict__ W1, const float* __restrict__ b1,
               const float* __restrict__ Wr1, const float* __restrict__ br1,
               float* __restrict__ idW, float* __restrict__ opWb, float* __restrict__ tidWb){
  int b = blockIdx.x, tid = threadIdx.x;
  if (b < 64){
    for (int j = tid; j < 512; j += 256){
      float v = 0.f;
      #pragma unroll
      for (int u = 0; u < 4; u++) v = fmaf(id_embeds[b*4+u], W1[(size_t)(512+u)*512 + j], v);
      idW[b*512 + j] = v;
    }
  } else if (b < 67){
    int o = b - 64;
    for (int j = tid; j < 512; j += 256){
      float v = b1[j];
      for (int u = 0; u < 256; u++) v = fmaf(op_emb[o*256+u], W1[(size_t)(516+u)*512 + j], v);
      opWb[o*512 + j] = v;
    }
  } else {
    for (int idx = tid; idx < 2048; idx += 256){
      int t = idx >> 5, c = idx & 31;
      float v = br1[c];
      #pragma unroll
      for (int u = 0; u < 4; u++) v = fmaf(tid_emb[t*4+u], Wr1[(512+u)*32 + c], v);
      tidWb[idx] = v;
    }
  }
}

// ------------------------------- active compaction -------------------------
// active_idx = where(!done, size=N, fill=0); meta[0]=num_active, meta[1]=winner slot for patch 0
__global__ __launch_bounds__(1024)
void k_scan(const int* __restrict__ done, int* __restrict__ aidx, int* __restrict__ meta){
  __shared__ int cnt[1024];
  int tid = threadIdx.x;
  int base = tid * 32;
  unsigned flags = 0; int c = 0;
  #pragma unroll
  for (int i = 0; i < 32; i++){
    int f = (done[base + i] == 0);
    flags |= ((unsigned)f) << i;
    c += f;
  }
  cnt[tid] = c;
  __syncthreads();
  int val = c;
  for (int off = 1; off < 1024; off <<= 1){
    int v = (tid >= off) ? cnt[tid - off] : 0;
    __syncthreads();
    val += v; cnt[tid] = val;
    __syncthreads();
  }
  int pos = val - c;                     // exclusive prefix
  for (int i = 0; i < 32; i++){
    if ((flags >> i) & 1u) aidx[pos++] = base + i;
  }
  __syncthreads();
  int na = cnt[1023];
  for (int j = na + tid; j < NPATCH; j += 1024) aidx[j] = 0;   // fill_value=0
  if (tid == 0){
    meta[0] = na;
    meta[1] = (na < NPATCH) ? (NPATCH - 1) : 0;   // last-writer-wins slot for patch 0
  }
}

// ------------------------------- gather + op sampling ----------------------
__global__ __launch_bounds__(256)
void k_gather(const int* __restrict__ aidx, const int* __restrict__ tempers,
              const uint32_t* __restrict__ keys, const float* __restrict__ logp3,
              int hop, int* __restrict__ t_act, int* __restrict__ op_idx){
  int s = blockIdx.x*256 + threadIdx.x;
  int p = aidx[s];
  t_act[s] = tempers[p];
  uint32_t k0 = keys[2 + 4*hop], k1 = keys[3 + 4*hop];
  float best = 0.f; int bi = 0;
  #pragma unroll
  for (int c = 0; c < 3; c++){
    float v = jgumbel(jbits32(k0, k1, (uint32_t)(3*s + c), 3u*NPATCH)) + logp3[c];
    if (c == 0 || v > best){ best = v; bi = c; }
  }
  op_idx[s] = bi;
}

// ------------------------------- fp32 tiled GEMM ---------------------------
// C[M,Ncols] = epilogue(A[M,512] @ B[512,Ncols]); K fixed at 512.
// MODE 0: +bias, relu (layer2).  MODE 1: A-rows gathered via aidx,
// +idW[t]+opWb[op], relu (layer1).  MODE 2: +bias (pred).
template<int MODE>
__global__ __launch_bounds__(256)
void k_gemm(const float* __restrict__ A, const float* __restrict__ B, float* __restrict__ C,
            int Ncols,
            const int* __restrict__ aidx,
            const float* __restrict__ bias,
            const float* __restrict__ idW, const float* __restrict__ opWb,
            const int* __restrict__ t_act, const int* __restrict__ op_idx){
  __shared__ float As[16][128];
  __shared__ float Bs[16][128];
  const int tid = threadIdx.x;
  const int bx = blockIdx.x, by = blockIdx.y;
  const int tx = tid & 15, ty = tid >> 4;
  const int lr = tid >> 1, lhalf = tid & 1;
  const int srow = by*128 + lr;
  const int arow = (MODE == 1) ? aidx[srow] : srow;
  const float* Ap = A + (size_t)arow*512 + lhalf*8;
  const float* Bp = B + (size_t)(tid >> 4)*Ncols + bx*128 + (tid & 15)*8;

  float acc[8][8];
  #pragma unroll
  for (int i = 0; i < 8; i++)
    #pragma unroll
    for (int j = 0; j < 8; j++) acc[i][j] = 0.f;

  for (int kt = 0; kt < 512; kt += 16){
    float4 a0 = *(const float4*)(Ap + kt);
    float4 a1 = *(const float4*)(Ap + kt + 4);
    float4 g0 = *(const float4*)(Bp + (size_t)kt*Ncols);
    float4 g1 = *(const float4*)(Bp + (size_t)kt*Ncols + 4);
    __syncthreads();
    As[lhalf*8+0][lr] = a0.x; As[lhalf*8+1][lr] = a0.y;
    As[lhalf*8+2][lr] = a0.z; As[lhalf*8+3][lr] = a0.w;
    As[lhalf*8+4][lr] = a1.x; As[lhalf*8+5][lr] = a1.y;
    As[lhalf*8+6][lr] = a1.z; As[lhalf*8+7][lr] = a1.w;
    *(float4*)&Bs[tid>>4][(tid&15)*8]     = g0;
    *(float4*)&Bs[tid>>4][(tid&15)*8 + 4] = g1;
    __syncthreads();
    #pragma unroll
    for (int k = 0; k < 16; k++){
      float4 av0 = *(float4*)&As[k][ty*8];
      float4 av1 = *(float4*)&As[k][ty*8+4];
      float4 bv0 = *(float4*)&Bs[k][tx*4];        // cols 4tx..4tx+3   (2-way max)
      float4 bv1 = *(float4*)&Bs[k][64 + tx*4];   // cols 64+4tx..+3
      float av[8] = {av0.x,av0.y,av0.z,av0.w,av1.x,av1.y,av1.z,av1.w};
      float bv[8] = {bv0.x,bv0.y,bv0.z,bv0.w,bv1.x,bv1.y,bv1.z,bv1.w};
      #pragma unroll
      for (int i = 0; i < 8; i++)
        #pragma unroll
        for (int j = 0; j < 8; j++)
          acc[i][j] = fmaf(av[i], bv[j], acc[i][j]);
    }
  }

  const int col0a = bx*128 + tx*4;
  const int col0b = col0a + 64;
  #pragma unroll
  for (int i = 0; i < 8; i++){
    int s = by*128 + ty*8 + i;
    float adda[4], addb[4];
    if (MODE == 1){
      int t = t_act[s], o = op_idx[s];
      float4 ia = *(const float4*)&idW[t*512 + col0a];
      float4 ib = *(const float4*)&idW[t*512 + col0b];
      float4 oa = *(const float4*)&opWb[o*512 + col0a];
      float4 ob = *(const float4*)&opWb[o*512 + col0b];
      adda[0]=ia.x+oa.x; adda[1]=ia.y+oa.y; adda[2]=ia.z+oa.z; adda[3]=ia.w+oa.w;
      addb[0]=ib.x+ob.x; addb[1]=ib.y+ob.y; addb[2]=ib.z+ob.z; addb[3]=ib.w+ob.w;
    } else {
      float4 ba = *(const float4*)&bias[col0a];
      float4 bb = *(const float4*)&bias[col0b];
      adda[0]=ba.x; adda[1]=ba.y; adda[2]=ba.z; adda[3]=ba.w;
      addb[0]=bb.x; addb[1]=bb.y; addb[2]=bb.z; addb[3]=bb.w;
    }
    float4 va, vb;
    float* pa = &va.x; float* pb = &vb.x;
    #pragma unroll
    for (int j = 0; j < 4; j++){
      float v0 = acc[i][j]   + adda[j];
      float v1 = acc[i][j+4] + addb[j];
      if (MODE != 2){ v0 = fmaxf(v0, 0.f); v1 = fmaxf(v1, 0.f); }
      pa[j] = v0; pb[j] = v1;
    }
    *(float4*)(C + (size_t)s*Ncols + col0a) = va;
    *(float4*)(C + (size_t)s*Ncols + col0b) = vb;
  }
}

// ------------------------------- routing + sample + scatter ----------------
// per slot: l32 = relu(h2 @ Wr1[0:512] + tidWb[t]); logits = l32 @ Wr2 + br2;
// sampled = argmax(log_softmax(logits) + gumbel(sk)); scatter last-wins.
__global__ __launch_bounds__(256)
void k_route(const float* __restrict__ h2, const float* __restrict__ Wr1,
             const float* __restrict__ Wr2, const float* __restrict__ br2,
             const float* __restrict__ tidWb,
             const int* __restrict__ t_act, const int* __restrict__ aidx,
             const int* __restrict__ meta, const uint32_t* __restrict__ keys, int hop,
             float* __restrict__ states, int* __restrict__ tempers, int* __restrict__ done){
  __shared__ float Wr1s[256][32];  // 32 KB (one K-half at a time)
  __shared__ float h2s[8][512];    // 16 KB
  __shared__ float l32[8][32];     // 1 KB

  const int tid = threadIdx.x;
  const int s0 = blockIdx.x * 8;

  // stage h2 rows for this block's 8 slots
  for (int i4 = tid; i4 < 8*128; i4 += 256){
    int sl = i4 >> 7, q = i4 & 127;
    *(float4*)&h2s[sl][q*4] = *(const float4*)&h2[(size_t)(s0+sl)*512 + q*4];
  }

  const int lane = tid & 63, w = tid >> 6;
  const int half = lane >> 5, col = lane & 31;
  const int sl = w*2 + half;
  const int s  = s0 + sl;
  const int t  = t_act[s];
  float acc = tidWb[t*32 + col];

  for (int kh = 0; kh < 2; kh++){
    __syncthreads();
    for (int idx = tid; idx < 256*32; idx += 256)
      Wr1s[idx >> 5][idx & 31] = Wr1[kh*8192 + idx];
    __syncthreads();
    const int kb = kh * 256;
    #pragma unroll 4
    for (int k4 = 0; k4 < 64; k4++){
      float4 hv = *(float4*)&h2s[sl][kb + k4*4];
      acc = fmaf(hv.x, Wr1s[k4*4+0][col], acc);
      acc = fmaf(hv.y, Wr1s[k4*4+1][col], acc);
      acc = fmaf(hv.z, Wr1s[k4*4+2][col], acc);
      acc = fmaf(hv.w, Wr1s[k4*4+3][col], acc);
    }
  }
  l32[sl][col] = fmaxf(acc, 0.f);
  __syncthreads();

  const uint32_t sk0 = keys[4 + 4*hop], sk1 = keys[5 + 4*hop];
  const uint32_t ntot = 65u * NPATCH;
  int smp[2];
  for (int pass = 0; pass < 2; pass++){
    const int psl = w*2 + pass;
    const int ps  = s0 + psl;
    const int c = lane;                     // 0..63; c=64 handled separately
    float lg = br2[c];
    #pragma unroll
    for (int k = 0; k < 32; k++) lg = fmaf(l32[psl][k], Wr2[k*65 + c], lg);
    float lg64 = br2[64];
    #pragma unroll
    for (int k = 0; k < 32; k++) lg64 = fmaf(l32[psl][k], Wr2[k*65 + 64], lg64);
    // max over all 65
    float m = lg;
    for (int off = 32; off; off >>= 1) m = fmaxf(m, __shfl_xor(m, off));
    m = fmaxf(m, lg64);
    // logsumexp
    float se = expf(lg - m);
    for (int off = 32; off; off >>= 1) se += __shfl_xor(se, off);
    se += expf(lg64 - m);
    float L = logf(se);
    // gumbel + argmax (first-index tie-break)
    float g = jgumbel(jbits32(sk0, sk1, (uint32_t)(65*ps + c), ntot));
    float v = (lg - m) - L + g;
    int idx = c;
    for (int off = 32; off; off >>= 1){
      float ov = __shfl_xor(v, off);
      int   oi = __shfl_xor(idx, off);
      if (ov > v || (ov == v && oi < idx)){ v = ov; idx = oi; }
    }
    float g64 = jgumbel(jbits32(sk0, sk1, (uint32_t)(65*ps + 64), ntot));
    float v64 = (lg64 - m) - L + g64;
    if (v64 > v) idx = 64;                 // index 64 is last: strict >
    smp[pass] = idx;
  }

  // scatter: last-writer-wins -> patch 0 written only by winner slot
  const int mysmp = smp[half];
  const int p = aidx[s];
  const int w0v = meta[1];
  const bool allowed = (p != 0) || (s == w0v);
  if (allowed){
    const float4* src = (const float4*)&h2s[sl][0];
    float4* dst = (float4*)(states + (size_t)p*512);
    for (int q = col; q < 128; q += 32) dst[q] = src[q];
    if (col == 0){
      tempers[p] = (mysmp < 63) ? mysmp : 63;
      done[p]    = (mysmp == 64) ? 1 : 0;
    }
  }
}

// ------------------------------- latent (mean over patches) ----------------
__global__ __launch_bounds__(256)
void k_latent(const float* __restrict__ states, float* __restrict__ out){
  int idx = blockIdx.x*256 + threadIdx.x;       // < 2048*512
  int b = idx >> 9, j = idx & 511;
  float s = 0.f;
  #pragma unroll
  for (int u = 0; u < 16; u++) s += states[(size_t)(b*16 + u)*512 + j];
  out[idx] = s * 0.0625f;
}

// ------------------------------- launch ------------------------------------
extern "C" void kernel_launch(void* const* d_in, const int* in_sizes, int n_in,
                              void* d_out, int out_size, void* d_ws, size_t ws_size,
                              hipStream_t stream) {
  (void)in_sizes; (void)n_in; (void)out_size;
  const float* x         = (const float*)d_in[0];
  const float* op_emb    = (const float*)d_in[1];
  const float* op_logits = (const float*)d_in[2];
  const float* id_embeds = (const float*)d_in[3];
  const float* W1        = (const float*)d_in[4];
  const float* b1        = (const float*)d_in[5];
  const float* W2        = (const float*)d_in[6];
  const float* b2        = (const float*)d_in[7];
  const float* Wr1       = (const float*)d_in[8];
  const float* br1       = (const float*)d_in[9];
  const float* Wr2       = (const float*)d_in[10];
  const float* br2       = (const float*)d_in[11];
  const float* Wp        = (const float*)d_in[12];
  const float* bp        = (const float*)d_in[13];
  const float* tid_emb   = (const float*)d_in[14];
  const int*   seed      = (const int*)d_in[15];
  float* out = (float*)d_out;

  char* w = (char*)d_ws;
  uint32_t* keys = (uint32_t*)w;                 // 18 u32
  float* logp3   = (float*)(w + 128);
  int*   meta    = (int*)(w + 192);
  int*   tempers = (int*)(w + 1024);
  int*   done    = tempers + NPATCH;
  int*   t_act   = done + NPATCH;
  int*   op_idx  = t_act + NPATCH;
  int*   aidx    = op_idx + NPATCH;
  float* idW     = (float*)(aidx + NPATCH);      // 64*512
  float* opWb    = idW + 64*512;                 // 3*512
  float* tidWb   = opWb + 3*512;                 // 64*32

  const size_t BIG0 = 2u<<20;                    // big buffers start at 2 MB
  const size_t SB   = (size_t)NPATCH * 512 * sizeof(float);   // 64 MB
  float *states, *h1, *h2;
  bool copy_states;
  if (ws_size >= BIG0 + 3*SB){
    states = (float*)(w + BIG0);
    h1     = (float*)(w + BIG0 + SB);
    h2     = (float*)(w + BIG0 + 2*SB);
    copy_states = true;
  } else {
    // fallback: run in-place on the input (harness restores inputs per launch)
    states = (float*)d_in[0];
    h1     = (float*)(w + BIG0);
    h2     = (float*)(w + BIG0 + SB);
    copy_states = false;
  }

  k_keys<<<1, 64, 0, stream>>>(seed, op_logits, keys, logp3);
  k_init<<<NPATCH/256, 256, 0, stream>>>(keys, tempers, done);
  if (copy_states)
    hipMemcpyAsync(states, x, SB, hipMemcpyDeviceToDevice, stream);
  k_precomp<<<68, 256, 0, stream>>>(id_embeds, op_emb, tid_emb, W1, b1, Wr1, br1,
                                    idW, opWb, tidWb);

  for (int hop = 0; hop < NHOP; hop++){
    k_scan<<<1, 1024, 0, stream>>>(done, aidx, meta);
    k_gather<<<NPATCH/256, 256, 0, stream>>>(aidx, tempers, keys, logp3, hop, t_act, op_idx);
    k_gemm<1><<<dim3(4, NPATCH/128), 256, 0, stream>>>(states, W1, h1, 512,
                                    aidx, nullptr, idW, opWb, t_act, op_idx);
    k_gemm<0><<<dim3(4, NPATCH/128), 256, 0, stream>>>(h1, W2, h2, 512,
                                    nullptr, b2, nullptr, nullptr, nullptr, nullptr);
    k_route<<<NPATCH/8, 256, 0, stream>>>(h2, Wr1, Wr2, br2, tidWb, t_act, aidx,
                                    meta, keys, hop, states, tempers, done);
  }

  k_latent<<<(2048*512)/256, 256, 0, stream>>>(states, out);
  k_gemm<2><<<dim3(8192/128, 2048/128), 256, 0, stream>>>(out, Wp, out + 2048*512, 8192,
                                    nullptr, bp, nullptr, nullptr, nullptr, nullptr);
}

// Round 2
// 1572.584 us; speedup vs baseline: 1.4600x; 1.4600x over previous
//
#include <hip/hip_runtime.h>
#include <cstdint>
#include <cstddef>

// ---------------------------------------------------------------------------
// TemperGraph on gfx950 — R2: bf16x3-split MFMA GEMMs (6-term, fp32-class
// accuracy), exact JAX threefry sampling preserved from R1 (passed).
// Fallback to R1's fp32-VALU pipeline if ws_size is too small.
// ---------------------------------------------------------------------------

#define NPATCH 32768          // B(2048) * num_patches(16)
#define NHOP 4

typedef unsigned short u16;
typedef __attribute__((ext_vector_type(8))) short short8;   // 8 bf16 (4 VGPRs)
typedef __attribute__((ext_vector_type(4))) float f32x4;

// ------------------------------- threefry ----------------------------------
__device__ __forceinline__ uint32_t rotl32(uint32_t x, int r){ return (x<<r)|(x>>(32-r)); }

__device__ __forceinline__ void tf2x32(uint32_t k0, uint32_t k1, uint32_t x0, uint32_t x1,
                                       uint32_t& o0, uint32_t& o1){
  uint32_t k2 = k0 ^ k1 ^ 0x1BD11BDAu;
  x0 += k0; x1 += k1;
#define TFR(r) { x0 += x1; x1 = rotl32(x1,(r)); x1 ^= x0; }
  TFR(13) TFR(15) TFR(26) TFR(6)   x0 += k1; x1 += k2 + 1u;
  TFR(17) TFR(29) TFR(16) TFR(24)  x0 += k2; x1 += k0 + 2u;
  TFR(13) TFR(15) TFR(26) TFR(6)   x0 += k0; x1 += k1 + 3u;
  TFR(17) TFR(29) TFR(16) TFR(24)  x0 += k1; x1 += k2 + 4u;
  TFR(13) TFR(15) TFR(26) TFR(6)   x0 += k2; x1 += k0 + 5u;
#undef TFR
  o0 = x0; o1 = x1;
}

__device__ __forceinline__ uint32_t jbits32(uint32_t k0, uint32_t k1, uint32_t idx){
  uint32_t a, b; tf2x32(k0, k1, 0u, idx, a, b);
  return a ^ b;
}

__device__ __forceinline__ void jsplit(uint32_t& r0, uint32_t& r1, uint32_t& c0, uint32_t& c1){
  uint32_t n0, n1;
  tf2x32(r0, r1, 0u, 0u, n0, n1);
  tf2x32(r0, r1, 0u, 1u, c0, c1);
  r0 = n0; r1 = n1;
}

__device__ __forceinline__ float jgumbel(uint32_t bits){
  float f = __uint_as_float(0x3f800000u | (bits >> 9)) - 1.0f;
  float u = fmaxf(f, 1.17549435e-38f);
  return -logf(-logf(u));
}

// ------------------------------- bf16 split helpers ------------------------
__device__ __forceinline__ u16 bf16rne(float x){
  uint32_t u = __float_as_uint(x);
  return (u16)((u + 0x7fffu + ((u >> 16) & 1u)) >> 16);
}
__device__ __forceinline__ float bf2f(u16 h){ return __uint_as_float(((uint32_t)h) << 16); }
__device__ __forceinline__ void split3(float v, u16& a0, u16& a1, u16& a2){
  a0 = bf16rne(v); float r = v - bf2f(a0);
  a1 = bf16rne(r); r -= bf2f(a1);
  a2 = bf16rne(r);
}

// ------------------------------- key derivation ----------------------------
__global__ void k_keys(const int* __restrict__ seed, const float* __restrict__ op_logits,
                       uint32_t* __restrict__ keys, float* __restrict__ logp3){
  if (threadIdx.x != 0 || blockIdx.x != 0) return;
  uint32_t r0 = 0u, r1 = (uint32_t)seed[0];
  uint32_t c0, c1;
  jsplit(r0, r1, c0, c1); keys[0] = c0; keys[1] = c1;          // tk
  for (int h = 0; h < NHOP; h++){
    jsplit(r0, r1, c0, c1); keys[2 + 4*h] = c0; keys[3 + 4*h] = c1;  // ok_h
    jsplit(r0, r1, c0, c1); keys[4 + 4*h] = c0; keys[5 + 4*h] = c1;  // sk_h
  }
  float l0 = op_logits[0], l1 = op_logits[1], l2 = op_logits[2];
  float mm = fmaxf(l0, fmaxf(l1, l2));
  float e0 = expf(l0-mm), e1 = expf(l1-mm), e2 = expf(l2-mm);
  float ssum = e0 + e1 + e2;
  logp3[0] = logf(e0/ssum); logp3[1] = logf(e1/ssum); logp3[2] = logf(e2/ssum);
}

// ------------------------------- init --------------------------------------
__global__ __launch_bounds__(256)
void k_init(const uint32_t* __restrict__ keys, int* __restrict__ tempers, int* __restrict__ done){
  int i = blockIdx.x*256 + threadIdx.x;
  uint32_t b = jbits32(keys[0], keys[1], (uint32_t)(NPATCH + i));
  tempers[i] = (int)(b & 63u);
  done[i] = 0;
}

// ------------------------------- precompute --------------------------------
__global__ __launch_bounds__(256)
void k_precomp(const float* __restrict__ id_embeds, const float* __restrict__ op_emb,
               const float* __restrict__ tid_emb,
               const float* __restrict__ W1, const float* __restrict__ b1,
               const float* __restrict__ Wr1, const float* __restrict__ br1,
               float* __restrict__ idW, float* __restrict__ opWb, float* __restrict__ tidWb){
  int b = blockIdx.x, tid = threadIdx.x;
  if (b < 64){
    for (int j = tid; j < 512; j += 256){
      float v = 0.f;
      #pragma unroll
      for (int u = 0; u < 4; u++) v = fmaf(id_embeds[b*4+u], W1[(size_t)(512+u)*512 + j], v);
      idW[b*512 + j] = v;
    }
  } else if (b < 67){
    int o = b - 64;
    for (int j = tid; j < 512; j += 256){
      float v = b1[j];
      for (int u = 0; u < 256; u++) v = fmaf(op_emb[o*256+u], W1[(size_t)(516+u)*512 + j], v);
      opWb[o*512 + j] = v;
    }
  } else {
    for (int idx = tid; idx < 2048; idx += 256){
      int t = idx >> 5, c = idx & 31;
      float v = br1[c];
      #pragma unroll
      for (int u = 0; u < 4; u++) v = fmaf(tid_emb[t*4+u], Wr1[(512+u)*32 + c], v);
      tidWb[idx] = v;
    }
  }
}

// ------------------------------- weight transpose + split ------------------
// W1T/W2T: 3 planes of [512][512] (k contiguous). WpT: 2 planes of [8192][512].
__global__ __launch_bounds__(256)
void k_splitW(const float* __restrict__ W1, const float* __restrict__ W2,
              const float* __restrict__ Wp,
              u16* __restrict__ W1T, u16* __restrict__ W2T, u16* __restrict__ WpT){
  __shared__ float t[32][33];
  int blk = blockIdx.x;
  const float* src; u16* dst; int N; int deg; size_t pst; int tb;
  if (blk < 256){ src = W1; dst = W1T; N = 512; deg = 3; pst = (size_t)512*512; tb = blk; }
  else if (blk < 512){ src = W2; dst = W2T; N = 512; deg = 3; pst = (size_t)512*512; tb = blk - 256; }
  else { src = Wp; dst = WpT; N = 8192; deg = 2; pst = (size_t)8192*512; tb = blk - 512; }
  int n0 = (tb >> 4)*32, k0 = (tb & 15)*32;
  int r = threadIdx.x >> 5, c = threadIdx.x & 31;
  for (int rr = r; rr < 32; rr += 8)
    t[rr][c] = src[(size_t)(k0+rr)*N + n0 + c];
  __syncthreads();
  for (int rr = r; rr < 32; rr += 8){
    float v = t[c][rr];                       // src[k0+c][n0+rr]
    u16 a0 = bf16rne(v); float rem = v - bf2f(a0);
    u16 a1 = bf16rne(rem);
    size_t o = (size_t)(n0+rr)*512 + k0 + c;
    dst[o] = a0; dst[pst + o] = a1;
    if (deg == 3){ rem -= bf2f(a1); dst[2*pst + o] = bf16rne(rem); }
  }
}

// ------------------------------- x -> states planes ------------------------
__global__ __launch_bounds__(256)
void k_xsplit(const float* __restrict__ x, u16* __restrict__ sP){
  size_t i = ((size_t)blockIdx.x*256 + threadIdx.x)*4;
  float4 v = *(const float4*)(x + i);
  ushort4 p0, p1, p2;
  split3(v.x, p0.x, p1.x, p2.x); split3(v.y, p0.y, p1.y, p2.y);
  split3(v.z, p0.z, p1.z, p2.z); split3(v.w, p0.w, p1.w, p2.w);
  const size_t SP = (size_t)NPATCH*512;
  *(ushort4*)(sP + i) = p0; *(ushort4*)(sP + SP + i) = p1; *(ushort4*)(sP + 2*SP + i) = p2;
}

// ------------------------------- active compaction -------------------------
__global__ __launch_bounds__(1024)
void k_scan(const int* __restrict__ done, int* __restrict__ aidx, int* __restrict__ meta){
  __shared__ int cnt[1024];
  int tid = threadIdx.x;
  int base = tid * 32;
  unsigned flags = 0; int c = 0;
  #pragma unroll
  for (int i = 0; i < 32; i++){
    int f = (done[base + i] == 0);
    flags |= ((unsigned)f) << i;
    c += f;
  }
  cnt[tid] = c;
  __syncthreads();
  int val = c;
  for (int off = 1; off < 1024; off <<= 1){
    int v = (tid >= off) ? cnt[tid - off] : 0;
    __syncthreads();
    val += v; cnt[tid] = val;
    __syncthreads();
  }
  int pos = val - c;
  for (int i = 0; i < 32; i++){
    if ((flags >> i) & 1u) aidx[pos++] = base + i;
  }
  __syncthreads();
  int na = cnt[1023];
  for (int j = na + tid; j < NPATCH; j += 1024) aidx[j] = 0;
  if (tid == 0){
    meta[0] = na;
    meta[1] = (na < NPATCH) ? (NPATCH - 1) : 0;
  }
}

// ------------------------------- gather + op sampling ----------------------
__global__ __launch_bounds__(256)
void k_gather(const int* __restrict__ aidx, const int* __restrict__ tempers,
              const uint32_t* __restrict__ keys, const float* __restrict__ logp3,
              int hop, int* __restrict__ t_act, int* __restrict__ op_idx){
  int s = blockIdx.x*256 + threadIdx.x;
  int p = aidx[s];
  t_act[s] = tempers[p];
  uint32_t k0 = keys[2 + 4*hop], k1 = keys[3 + 4*hop];
  float best = 0.f; int bi = 0;
  #pragma unroll
  for (int c = 0; c < 3; c++){
    float v = jgumbel(jbits32(k0, k1, (uint32_t)(3*s + c))) + logp3[c];
    if (c == 0 || v > best){ best = v; bi = c; }
  }
  op_idx[s] = bi;
}

// ------------------------------- bf16x3 MFMA GEMM --------------------------
// C[M,*] = epilogue( sum over split-plane pairs of Ap @ BpT ), K = 512.
// A planes: [DEG][M][512] bf16 (k contiguous). B planes: [DEG][N][512] (B^T).
// MODE 1: A-rows gathered via aidx, + idW[t]+opWb[op], relu, write 3 bf16 planes.
// MODE 0: + bias, relu, write fp32.
// MODE 2: + bias, write fp32 (DEG=2, 3 terms).
template<int MODE, int DEG>
__global__ __launch_bounds__(256, 2)
void k_mgemm(const u16* __restrict__ Ap, const u16* __restrict__ Bp,
             float* __restrict__ outF, u16* __restrict__ outP,
             const int* __restrict__ aidx, const float* __restrict__ bias,
             const float* __restrict__ idW, const float* __restrict__ opWb,
             const int* __restrict__ t_act, const int* __restrict__ op_idx,
             int Ncols, size_t aStride, size_t bStride, size_t oStride){
  __shared__ u16 As[3*4096];     // [plane][128 rows][32 k]
  __shared__ u16 Bs[3*4096];
  const int tid = threadIdx.x;
  const int L = tid & 63, w = tid >> 6;
  const int m0 = blockIdx.y*128, n0 = blockIdx.x*128;
  const int wr = w >> 1, wc = w & 1;

  // -------- staging setup: waves 0,1 stage A; waves 2,3 stage B ----------
  const int SPW = DEG*4;                  // segments (1 KB each) per wave
  const bool isA = (w < 2);
  const u16* gB = isA ? Ap : Bp;
  u16* lB = isA ? As : Bs;
  const size_t pstride = isA ? aStride : bStride;
  uint32_t goff[12], loff[12];
  #pragma unroll
  for (int q = 0; q < SPW; q++){
    int ss = (w & 1)*SPW + q;
    int p = ss >> 3, rb = ss & 7;
    int row = rb*16 + (L >> 2);
    int ke  = (L & 3)*8;
    int grow;
    if (isA) grow = (MODE == 1) ? aidx[m0 + row] : (m0 + row);
    else     grow = n0 + row;
    goff[q] = (uint32_t)((p*pstride + (size_t)grow*512 + ke)*2);
    loff[q] = (uint32_t)(p*4096 + rb*512 + L*8);
  }

  f32x4 acc[4][4];
  #pragma unroll
  for (int i = 0; i < 4; i++)
    #pragma unroll
    for (int j = 0; j < 4; j++) acc[i][j] = (f32x4)0.f;

  short8 st[12];
  #pragma unroll
  for (int q = 0; q < SPW; q++)
    st[q] = *(const short8*)((const char*)gB + goff[q]);

  for (int kt = 0; kt < 512; kt += 32){
    __syncthreads();
    #pragma unroll
    for (int q = 0; q < SPW; q++) *(short8*)&lB[loff[q]] = st[q];
    __syncthreads();
    if (kt + 32 < 512){
      #pragma unroll
      for (int q = 0; q < SPW; q++)
        st[q] = *(const short8*)((const char*)gB + goff[q] + (size_t)(kt+32)*2);
    }
    // B fragments resident for all planes
    short8 bfr[DEG][4];
    #pragma unroll
    for (int pb = 0; pb < DEG; pb++)
      #pragma unroll
      for (int j = 0; j < 4; j++)
        bfr[pb][j] = *(const short8*)&Bs[pb*4096 + (wc*64 + j*16 + (L & 15))*32 + (L >> 4)*8];
    #pragma unroll
    for (int pa = 0; pa < DEG; pa++){
      short8 af[4];
      #pragma unroll
      for (int i = 0; i < 4; i++)
        af[i] = *(const short8*)&As[pa*4096 + (wr*64 + i*16 + (L & 15))*32 + (L >> 4)*8];
      #pragma unroll
      for (int pb = 0; pb < DEG - pa; pb++)
        #pragma unroll
        for (int i = 0; i < 4; i++)
          #pragma unroll
          for (int j = 0; j < 4; j++)
            acc[i][j] = __builtin_amdgcn_mfma_f32_16x16x32_bf16(af[i], bfr[pb][j], acc[i][j], 0, 0, 0);
    }
  }

  // -------- epilogue: C row = m0+wr*64+i*16+(L>>4)*4+reg, col = n0+wc*64+j*16+(L&15)
  const int rbase = m0 + wr*64 + (L >> 4)*4;
  const int cbase = n0 + wc*64 + (L & 15);
  #pragma unroll
  for (int i = 0; i < 4; i++){
    #pragma unroll
    for (int reg = 0; reg < 4; reg++){
      int r = rbase + i*16 + reg;
      if (MODE == 1){
        int t = t_act[r], o = op_idx[r];
        #pragma unroll
        for (int j = 0; j < 4; j++){
          int c = cbase + j*16;
          float v = acc[i][j][reg] + idW[t*512 + c] + opWb[o*512 + c];
          v = fmaxf(v, 0.f);
          u16 a0, a1, a2; split3(v, a0, a1, a2);
          size_t off = (size_t)r*512 + c;
          outP[off] = a0; outP[oStride + off] = a1; outP[2*oStride + off] = a2;
        }
      } else {
        #pragma unroll
        for (int j = 0; j < 4; j++){
          int c = cbase + j*16;
          float v = acc[i][j][reg] + bias[c];
          if (MODE == 0) v = fmaxf(v, 0.f);
          outF[(size_t)r*Ncols + c] = v;
        }
      }
    }
  }
}

// ------------------------------- routing + sample + scatter (planes) -------
__global__ __launch_bounds__(256)
void k_route2(const float* __restrict__ h2, const float* __restrict__ Wr1,
              const float* __restrict__ Wr2, const float* __restrict__ br2,
              const float* __restrict__ tidWb,
              const int* __restrict__ t_act, const int* __restrict__ aidx,
              const int* __restrict__ meta, const uint32_t* __restrict__ keys, int hop,
              u16* __restrict__ sP, int* __restrict__ tempers, int* __restrict__ done){
  __shared__ float Wr1s[256][32];
  __shared__ float h2s[8][512];
  __shared__ float l32[8][32];

  const int tid = threadIdx.x;
  const int s0 = blockIdx.x * 8;

  for (int i4 = tid; i4 < 8*128; i4 += 256){
    int sl = i4 >> 7, q = i4 & 127;
    *(float4*)&h2s[sl][q*4] = *(const float4*)&h2[(size_t)(s0+sl)*512 + q*4];
  }

  const int lane = tid & 63, w = tid >> 6;
  const int half = lane >> 5, col = lane & 31;
  const int sl = w*2 + half;
  const int s  = s0 + sl;
  const int t  = t_act[s];
  float acc = tidWb[t*32 + col];

  for (int kh = 0; kh < 2; kh++){
    __syncthreads();
    for (int idx = tid; idx < 256*32; idx += 256)
      Wr1s[idx >> 5][idx & 31] = Wr1[kh*8192 + idx];
    __syncthreads();
    const int kb = kh * 256;
    #pragma unroll 4
    for (int k4 = 0; k4 < 64; k4++){
      float4 hv = *(float4*)&h2s[sl][kb + k4*4];
      acc = fmaf(hv.x, Wr1s[k4*4+0][col], acc);
      acc = fmaf(hv.y, Wr1s[k4*4+1][col], acc);
      acc = fmaf(hv.z, Wr1s[k4*4+2][col], acc);
      acc = fmaf(hv.w, Wr1s[k4*4+3][col], acc);
    }
  }
  l32[sl][col] = fmaxf(acc, 0.f);
  __syncthreads();

  const uint32_t sk0 = keys[4 + 4*hop], sk1 = keys[5 + 4*hop];
  int smp[2];
  for (int pass = 0; pass < 2; pass++){
    const int psl = w*2 + pass;
    const int ps  = s0 + psl;
    const int c = lane;
    float lg = br2[c];
    #pragma unroll
    for (int k = 0; k < 32; k++) lg = fmaf(l32[psl][k], Wr2[k*65 + c], lg);
    float lg64 = br2[64];
    #pragma unroll
    for (int k = 0; k < 32; k++) lg64 = fmaf(l32[psl][k], Wr2[k*65 + 64], lg64);
    float m = lg;
    for (int off = 32; off; off >>= 1) m = fmaxf(m, __shfl_xor(m, off));
    m = fmaxf(m, lg64);
    float se = expf(lg - m);
    for (int off = 32; off; off >>= 1) se += __shfl_xor(se, off);
    se += expf(lg64 - m);
    float Lse = logf(se);
    float g = jgumbel(jbits32(sk0, sk1, (uint32_t)(65*ps + c)));
    float v = (lg - m) - Lse + g;
    int idx = c;
    for (int off = 32; off; off >>= 1){
      float ov = __shfl_xor(v, off);
      int   oi = __shfl_xor(idx, off);
      if (ov > v || (ov == v && oi < idx)){ v = ov; idx = oi; }
    }
    float g64 = jgumbel(jbits32(sk0, sk1, (uint32_t)(65*ps + 64)));
    float v64 = (lg64 - m) - Lse + g64;
    if (v64 > v) idx = 64;
    smp[pass] = idx;
  }

  const int mysmp = smp[half];
  const int p = aidx[s];
  const int w0v = meta[1];
  const bool allowed = (p != 0) || (s == w0v);
  if (allowed){
    const size_t SP = (size_t)NPATCH*512;
    for (int q = col; q < 128; q += 32){
      float4 v = *(float4*)&h2s[sl][q*4];
      ushort4 p0, p1, p2;
      split3(v.x, p0.x, p1.x, p2.x); split3(v.y, p0.y, p1.y, p2.y);
      split3(v.z, p0.z, p1.z, p2.z); split3(v.w, p0.w, p1.w, p2.w);
      size_t o = (size_t)p*512 + q*4;
      *(ushort4*)(sP + o) = p0; *(ushort4*)(sP + SP + o) = p1; *(ushort4*)(sP + 2*SP + o) = p2;
    }
    if (col == 0){
      tempers[p] = (mysmp < 63) ? mysmp : 63;
      done[p]    = (mysmp == 64) ? 1 : 0;
    }
  }
}

// ------------------------------- latent (mean over patches) ----------------
__global__ __launch_bounds__(256)
void k_latent2(const u16* __restrict__ sP, float* __restrict__ outF, u16* __restrict__ latP){
  int idx = blockIdx.x*256 + threadIdx.x;       // < 2048*512
  int b = idx >> 9, j = idx & 511;
  const size_t SP = (size_t)NPATCH*512;
  float s = 0.f;
  #pragma unroll 4
  for (int u = 0; u < 16; u++){
    size_t e = (size_t)(b*16 + u)*512 + j;
    s += bf2f(sP[e]) + bf2f(sP[SP + e]) + bf2f(sP[2*SP + e]);
  }
  s *= 0.0625f;
  outF[idx] = s;
  u16 a0 = bf16rne(s);
  latP[idx] = a0;
  latP[(size_t)2048*512 + idx] = bf16rne(s - bf2f(a0));
}

// ===========================================================================
// ------------- R1 fallback pipeline (fp32 VALU GEMM), verbatim -------------
// ===========================================================================
template<int MODE>
__global__ __launch_bounds__(256)
void k_gemmF(const float* __restrict__ A, const float* __restrict__ B, float* __restrict__ C,
             int Ncols,
             const int* __restrict__ aidx,
             const float* __restrict__ bias,
             const float* __restrict__ idW, const float* __restrict__ opWb,
             const int* __restrict__ t_act, const int* __restrict__ op_idx){
  __shared__ float As[16][128];
  __shared__ float Bs[16][128];
  const int tid = threadIdx.x;
  const int bx = blockIdx.x, by = blockIdx.y;
  const int tx = tid & 15, ty = tid >> 4;
  const int lr = tid >> 1, lhalf = tid & 1;
  const int srow = by*128 + lr;
  const int arow = (MODE == 1) ? aidx[srow] : srow;
  const float* Ap = A + (size_t)arow*512 + lhalf*8;
  const float* Bp = B + (size_t)(tid >> 4)*Ncols + bx*128 + (tid & 15)*8;

  float acc[8][8];
  #pragma unroll
  for (int i = 0; i < 8; i++)
    #pragma unroll
    for (int j = 0; j < 8; j++) acc[i][j] = 0.f;

  for (int kt = 0; kt < 512; kt += 16){
    float4 a0 = *(const float4*)(Ap + kt);
    float4 a1 = *(const float4*)(Ap + kt + 4);
    float4 g0 = *(const float4*)(Bp + (size_t)kt*Ncols);
    float4 g1 = *(const float4*)(Bp + (size_t)kt*Ncols + 4);
    __syncthreads();
    As[lhalf*8+0][lr] = a0.x; As[lhalf*8+1][lr] = a0.y;
    As[lhalf*8+2][lr] = a0.z; As[lhalf*8+3][lr] = a0.w;
    As[lhalf*8+4][lr] = a1.x; As[lhalf*8+5][lr] = a1.y;
    As[lhalf*8+6][lr] = a1.z; As[lhalf*8+7][lr] = a1.w;
    *(float4*)&Bs[tid>>4][(tid&15)*8]     = g0;
    *(float4*)&Bs[tid>>4][(tid&15)*8 + 4] = g1;
    __syncthreads();
    #pragma unroll
    for (int k = 0; k < 16; k++){
      float4 av0 = *(float4*)&As[k][ty*8];
      float4 av1 = *(float4*)&As[k][ty*8+4];
      float4 bv0 = *(float4*)&Bs[k][tx*4];
      float4 bv1 = *(float4*)&Bs[k][64 + tx*4];
      float av[8] = {av0.x,av0.y,av0.z,av0.w,av1.x,av1.y,av1.z,av1.w};
      float bv[8] = {bv0.x,bv0.y,bv0.z,bv0.w,bv1.x,bv1.y,bv1.z,bv1.w};
      #pragma unroll
      for (int i = 0; i < 8; i++)
        #pragma unroll
        for (int j = 0; j < 8; j++)
          acc[i][j] = fmaf(av[i], bv[j], acc[i][j]);
    }
  }

  const int col0a = bx*128 + tx*4;
  const int col0b = col0a + 64;
  #pragma unroll
  for (int i = 0; i < 8; i++){
    int s = by*128 + ty*8 + i;
    float adda[4], addb[4];
    if (MODE == 1){
      int t = t_act[s], o = op_idx[s];
      float4 ia = *(const float4*)&idW[t*512 + col0a];
      float4 ib = *(const float4*)&idW[t*512 + col0b];
      float4 oa = *(const float4*)&opWb[o*512 + col0a];
      float4 ob = *(const float4*)&opWb[o*512 + col0b];
      adda[0]=ia.x+oa.x; adda[1]=ia.y+oa.y; adda[2]=ia.z+oa.z; adda[3]=ia.w+oa.w;
      addb[0]=ib.x+ob.x; addb[1]=ib.y+ob.y; addb[2]=ib.z+ob.z; addb[3]=ib.w+ob.w;
    } else {
      float4 ba = *(const float4*)&bias[col0a];
      float4 bb = *(const float4*)&bias[col0b];
      adda[0]=ba.x; adda[1]=ba.y; adda[2]=ba.z; adda[3]=ba.w;
      addb[0]=bb.x; addb[1]=bb.y; addb[2]=bb.z; addb[3]=bb.w;
    }
    float4 va, vb;
    float* pa = &va.x; float* pb = &vb.x;
    #pragma unroll
    for (int j = 0; j < 4; j++){
      float v0 = acc[i][j]   + adda[j];
      float v1 = acc[i][j+4] + addb[j];
      if (MODE != 2){ v0 = fmaxf(v0, 0.f); v1 = fmaxf(v1, 0.f); }
      pa[j] = v0; pb[j] = v1;
    }
    *(float4*)(C + (size_t)s*Ncols + col0a) = va;
    *(float4*)(C + (size_t)s*Ncols + col0b) = vb;
  }
}

__global__ __launch_bounds__(256)
void k_routeF(const float* __restrict__ h2, const float* __restrict__ Wr1,
              const float* __restrict__ Wr2, const float* __restrict__ br2,
              const float* __restrict__ tidWb,
              const int* __restrict__ t_act, const int* __restrict__ aidx,
              const int* __restrict__ meta, const uint32_t* __restrict__ keys, int hop,
              float* __restrict__ states, int* __restrict__ tempers, int* __restrict__ done){
  __shared__ float Wr1s[256][32];
  __shared__ float h2s[8][512];
  __shared__ float l32[8][32];

  const int tid = threadIdx.x;
  const int s0 = blockIdx.x * 8;

  for (int i4 = tid; i4 < 8*128; i4 += 256){
    int sl = i4 >> 7, q = i4 & 127;
    *(float4*)&h2s[sl][q*4] = *(const float4*)&h2[(size_t)(s0+sl)*512 + q*4];
  }

  const int lane = tid & 63, w = tid >> 6;
  const int half = lane >> 5, col = lane & 31;
  const int sl = w*2 + half;
  const int s  = s0 + sl;
  const int t  = t_act[s];
  float acc = tidWb[t*32 + col];

  for (int kh = 0; kh < 2; kh++){
    __syncthreads();
    for (int idx = tid; idx < 256*32; idx += 256)
      Wr1s[idx >> 5][idx & 31] = Wr1[kh*8192 + idx];
    __syncthreads();
    const int kb = kh * 256;
    #pragma unroll 4
    for (int k4 = 0; k4 < 64; k4++){
      float4 hv = *(float4*)&h2s[sl][kb + k4*4];
      acc = fmaf(hv.x, Wr1s[k4*4+0][col], acc);
      acc = fmaf(hv.y, Wr1s[k4*4+1][col], acc);
      acc = fmaf(hv.z, Wr1s[k4*4+2][col], acc);
      acc = fmaf(hv.w, Wr1s[k4*4+3][col], acc);
    }
  }
  l32[sl][col] = fmaxf(acc, 0.f);
  __syncthreads();

  const uint32_t sk0 = keys[4 + 4*hop], sk1 = keys[5 + 4*hop];
  int smp[2];
  for (int pass = 0; pass < 2; pass++){
    const int psl = w*2 + pass;
    const int ps  = s0 + psl;
    const int c = lane;
    float lg = br2[c];
    #pragma unroll
    for (int k = 0; k < 32; k++) lg = fmaf(l32[psl][k], Wr2[k*65 + c], lg);
    float lg64 = br2[64];
    #pragma unroll
    for (int k = 0; k < 32; k++) lg64 = fmaf(l32[psl][k], Wr2[k*65 + 64], lg64);
    float m = lg;
    for (int off = 32; off; off >>= 1) m = fmaxf(m, __shfl_xor(m, off));
    m = fmaxf(m, lg64);
    float se = expf(lg - m);
    for (int off = 32; off; off >>= 1) se += __shfl_xor(se, off);
    se += expf(lg64 - m);
    float Lse = logf(se);
    float g = jgumbel(jbits32(sk0, sk1, (uint32_t)(65*ps + c)));
    float v = (lg - m) - Lse + g;
    int idx = c;
    for (int off = 32; off; off >>= 1){
      float ov = __shfl_xor(v, off);
      int   oi = __shfl_xor(idx, off);
      if (ov > v || (ov == v && oi < idx)){ v = ov; idx = oi; }
    }
    float g64 = jgumbel(jbits32(sk0, sk1, (uint32_t)(65*ps + 64)));
    float v64 = (lg64 - m) - Lse + g64;
    if (v64 > v) idx = 64;
    smp[pass] = idx;
  }

  const int mysmp = smp[half];
  const int p = aidx[s];
  const int w0v = meta[1];
  const bool allowed = (p != 0) || (s == w0v);
  if (allowed){
    const float4* src = (const float4*)&h2s[sl][0];
    float4* dst = (float4*)(states + (size_t)p*512);
    for (int q = col; q < 128; q += 32) dst[q] = src[q];
    if (col == 0){
      tempers[p] = (mysmp < 63) ? mysmp : 63;
      done[p]    = (mysmp == 64) ? 1 : 0;
    }
  }
}

__global__ __launch_bounds__(256)
void k_latentF(const float* __restrict__ states, float* __restrict__ out){
  int idx = blockIdx.x*256 + threadIdx.x;
  int b = idx >> 9, j = idx & 511;
  float s = 0.f;
  #pragma unroll
  for (int u = 0; u < 16; u++) s += states[(size_t)(b*16 + u)*512 + j];
  out[idx] = s * 0.0625f;
}

// ------------------------------- launch ------------------------------------
extern "C" void kernel_launch(void* const* d_in, const int* in_sizes, int n_in,
                              void* d_out, int out_size, void* d_ws, size_t ws_size,
                              hipStream_t stream) {
  (void)in_sizes; (void)n_in; (void)out_size;
  const float* x         = (const float*)d_in[0];
  const float* op_emb    = (const float*)d_in[1];
  const float* op_logits = (const float*)d_in[2];
  const float* id_embeds = (const float*)d_in[3];
  const float* W1        = (const float*)d_in[4];
  const float* b1        = (const float*)d_in[5];
  const float* W2        = (const float*)d_in[6];
  const float* b2        = (const float*)d_in[7];
  const float* Wr1       = (const float*)d_in[8];
  const float* br1       = (const float*)d_in[9];
  const float* Wr2       = (const float*)d_in[10];
  const float* br2       = (const float*)d_in[11];
  const float* Wp        = (const float*)d_in[12];
  const float* bp        = (const float*)d_in[13];
  const float* tid_emb   = (const float*)d_in[14];
  const int*   seed      = (const int*)d_in[15];
  float* out = (float*)d_out;

  char* w = (char*)d_ws;
  uint32_t* keys = (uint32_t*)w;                 // @0
  float* logp3   = (float*)(w + 256);
  int*   meta    = (int*)(w + 512);
  int*   tempers = (int*)(w + 4096);
  int*   done    = tempers + NPATCH;
  int*   t_act   = done + NPATCH;
  int*   op_idx  = t_act + NPATCH;
  int*   aidx    = op_idx + NPATCH;
  float* idW     = (float*)(aidx + NPATCH);
  float* opWb    = idW + 64*512;
  float* tidWb   = opWb + 3*512;                 // ends < 1 MB

  const size_t SPh = (size_t)NPATCH*512;         // states/h1 plane elems
  u16* W1T     = (u16*)(w + (1u<<20));
  u16* W2T     = W1T + (size_t)3*512*512;
  u16* WpT     = W2T + (size_t)3*512*512;
  u16* latP    = WpT + (size_t)2*8192*512;
  u16* statesP = latP + (size_t)2*2048*512;
  u16* h1P     = statesP + 3*SPh;
  float* h2W   = (float*)(h1P + 3*SPh);
  const size_t NEED1 = (size_t)((char*)h2W - w);         // ~216 MB
  const size_t NEED2 = NEED1 + SPh*sizeof(float);        // +64 MB

  k_keys<<<1, 64, 0, stream>>>(seed, op_logits, keys, logp3);
  k_init<<<NPATCH/256, 256, 0, stream>>>(keys, tempers, done);
  k_precomp<<<68, 256, 0, stream>>>(id_embeds, op_emb, tid_emb, W1, b1, Wr1, br1,
                                    idW, opWb, tidWb);

  if (ws_size >= NEED1){
    // ---------------- bf16x3 MFMA path ----------------
    float* h2 = (ws_size >= NEED2) ? h2W : (float*)d_in[0];  // x dead after k_xsplit
    k_splitW<<<4608, 256, 0, stream>>>(W1, W2, Wp, W1T, W2T, WpT);
    k_xsplit<<<(NPATCH*512/4)/256, 256, 0, stream>>>(x, statesP);

    for (int hop = 0; hop < NHOP; hop++){
      k_scan<<<1, 1024, 0, stream>>>(done, aidx, meta);
      k_gather<<<NPATCH/256, 256, 0, stream>>>(aidx, tempers, keys, logp3, hop, t_act, op_idx);
      k_mgemm<1,3><<<dim3(4, NPATCH/128), 256, 0, stream>>>(
          statesP, W1T, nullptr, h1P, aidx, nullptr, idW, opWb, t_act, op_idx,
          512, SPh, (size_t)512*512, SPh);
      k_mgemm<0,3><<<dim3(4, NPATCH/128), 256, 0, stream>>>(
          h1P, W2T, h2, nullptr, nullptr, b2, nullptr, nullptr, nullptr, nullptr,
          512, SPh, (size_t)512*512, 0);
      k_route2<<<NPATCH/8, 256, 0, stream>>>(h2, Wr1, Wr2, br2, tidWb, t_act, aidx,
                                             meta, keys, hop, statesP, tempers, done);
    }

    k_latent2<<<(2048*512)/256, 256, 0, stream>>>(statesP, out, latP);
    k_mgemm<2,2><<<dim3(64, 16), 256, 0, stream>>>(
        latP, WpT, out + 2048*512, nullptr, nullptr, bp, nullptr, nullptr, nullptr, nullptr,
        8192, (size_t)2048*512, (size_t)8192*512, 0);
  } else {
    // ---------------- R1 fp32 fallback ----------------
    const size_t BIG0 = 2u<<20;
    const size_t SB   = (size_t)NPATCH * 512 * sizeof(float);
    float *states, *h1, *h2;
    bool copy_states;
    if (ws_size >= BIG0 + 3*SB){
      states = (float*)(w + BIG0);
      h1     = (float*)(w + BIG0 + SB);
      h2     = (float*)(w + BIG0 + 2*SB);
      copy_states = true;
    } else {
      states = (float*)d_in[0];
      h1     = (float*)(w + BIG0);
      h2     = (float*)(w + BIG0 + SB);
      copy_states = false;
    }
    if (copy_states)
      hipMemcpyAsync(states, x, SB, hipMemcpyDeviceToDevice, stream);

    for (int hop = 0; hop < NHOP; hop++){
      k_scan<<<1, 1024, 0, stream>>>(done, aidx, meta);
      k_gather<<<NPATCH/256, 256, 0, stream>>>(aidx, tempers, keys, logp3, hop, t_act, op_idx);
      k_gemmF<1><<<dim3(4, NPATCH/128), 256, 0, stream>>>(states, W1, h1, 512,
                                      aidx, nullptr, idW, opWb, t_act, op_idx);
      k_gemmF<0><<<dim3(4, NPATCH/128), 256, 0, stream>>>(h1, W2, h2, 512,
                                      nullptr, b2, nullptr, nullptr, nullptr, nullptr);
      k_routeF<<<NPATCH/8, 256, 0, stream>>>(h2, Wr1, Wr2, br2, tidWb, t_act, aidx,
                                      meta, keys, hop, states, tempers, done);
    }

    k_latentF<<<(2048*512)/256, 256, 0, stream>>>(states, out);
    k_gemmF<2><<<dim3(8192/128, 2048/128), 256, 0, stream>>>(out, Wp, out + 2048*512, 8192,
                                      nullptr, bp, nullptr, nullptr, nullptr, nullptr);
  }
}

// Round 3
// 1210.199 us; speedup vs baseline: 1.8972x; 1.2994x over previous
//
#include <hip/hip_runtime.h>
#include <cstdint>
#include <cstddef>

// ---------------------------------------------------------------------------
// TemperGraph on gfx950 — R3: fp16x2-split MFMA GEMMs (3 terms, residual
// plane scaled by 2^12 into a second accumulator -> fp32-class accuracy,
// no fp16-subnormal hazard), global_load_lds(16B) staging with XOR-swizzled
// global addresses (conflict-free LDS reads). Pred GEMM = 1-term fp16.
// Exact JAX threefry sampling preserved from R1/R2 (passed twice).
// ---------------------------------------------------------------------------

#define NPATCH 32768          // B(2048) * num_patches(16)
#define NHOP 4
#define RSCALE 4096.0f
#define RINV   2.44140625e-4f  // 2^-12

typedef unsigned short u16;
typedef __attribute__((ext_vector_type(8))) _Float16 half8;  // 8 f16 (4 VGPRs)
typedef __attribute__((ext_vector_type(4))) float f32x4;

// ------------------------------- threefry ----------------------------------
__device__ __forceinline__ uint32_t rotl32(uint32_t x, int r){ return (x<<r)|(x>>(32-r)); }

__device__ __forceinline__ void tf2x32(uint32_t k0, uint32_t k1, uint32_t x0, uint32_t x1,
                                       uint32_t& o0, uint32_t& o1){
  uint32_t k2 = k0 ^ k1 ^ 0x1BD11BDAu;
  x0 += k0; x1 += k1;
#define TFR(r) { x0 += x1; x1 = rotl32(x1,(r)); x1 ^= x0; }
  TFR(13) TFR(15) TFR(26) TFR(6)   x0 += k1; x1 += k2 + 1u;
  TFR(17) TFR(29) TFR(16) TFR(24)  x0 += k2; x1 += k0 + 2u;
  TFR(13) TFR(15) TFR(26) TFR(6)   x0 += k0; x1 += k1 + 3u;
  TFR(17) TFR(29) TFR(16) TFR(24)  x0 += k1; x1 += k2 + 4u;
  TFR(13) TFR(15) TFR(26) TFR(6)   x0 += k2; x1 += k0 + 5u;
#undef TFR
  o0 = x0; o1 = x1;
}

__device__ __forceinline__ uint32_t jbits32(uint32_t k0, uint32_t k1, uint32_t idx){
  uint32_t a, b; tf2x32(k0, k1, 0u, idx, a, b);
  return a ^ b;
}

__device__ __forceinline__ void jsplit(uint32_t& r0, uint32_t& r1, uint32_t& c0, uint32_t& c1){
  uint32_t n0, n1;
  tf2x32(r0, r1, 0u, 0u, n0, n1);
  tf2x32(r0, r1, 0u, 1u, c0, c1);
  r0 = n0; r1 = n1;
}

__device__ __forceinline__ float jgumbel(uint32_t bits){
  float f = __uint_as_float(0x3f800000u | (bits >> 9)) - 1.0f;
  float u = fmaxf(f, 1.17549435e-38f);
  return -logf(-logf(u));
}

// ------------------------------- fp16 split helpers ------------------------
union uhcv { _Float16 h; u16 u; };
__device__ __forceinline__ u16 f2h(float x){ uhcv t; t.h = (_Float16)x; return t.u; }
__device__ __forceinline__ float h2f(u16 b){ uhcv t; t.u = b; return (float)t.h; }
// plane0 = fp16(v); plane1 = fp16((v - plane0) * 2^12)  (residual pre-scaled)
__device__ __forceinline__ void split2s(float v, u16& a0, u16& a1){
  a0 = f2h(v);
  a1 = f2h((v - h2f(a0)) * RSCALE);
}

// ------------------------------- key derivation ----------------------------
__global__ void k_keys(const int* __restrict__ seed, const float* __restrict__ op_logits,
                       uint32_t* __restrict__ keys, float* __restrict__ logp3){
  if (threadIdx.x != 0 || blockIdx.x != 0) return;
  uint32_t r0 = 0u, r1 = (uint32_t)seed[0];
  uint32_t c0, c1;
  jsplit(r0, r1, c0, c1); keys[0] = c0; keys[1] = c1;          // tk
  for (int h = 0; h < NHOP; h++){
    jsplit(r0, r1, c0, c1); keys[2 + 4*h] = c0; keys[3 + 4*h] = c1;  // ok_h
    jsplit(r0, r1, c0, c1); keys[4 + 4*h] = c0; keys[5 + 4*h] = c1;  // sk_h
  }
  float l0 = op_logits[0], l1 = op_logits[1], l2 = op_logits[2];
  float mm = fmaxf(l0, fmaxf(l1, l2));
  float e0 = expf(l0-mm), e1 = expf(l1-mm), e2 = expf(l2-mm);
  float ssum = e0 + e1 + e2;
  logp3[0] = logf(e0/ssum); logp3[1] = logf(e1/ssum); logp3[2] = logf(e2/ssum);
}

// ------------------------------- init --------------------------------------
__global__ __launch_bounds__(256)
void k_init(const uint32_t* __restrict__ keys, int* __restrict__ tempers, int* __restrict__ done){
  int i = blockIdx.x*256 + threadIdx.x;
  uint32_t b = jbits32(keys[0], keys[1], (uint32_t)(NPATCH + i));
  tempers[i] = (int)(b & 63u);
  done[i] = 0;
}

// ------------------------------- precompute --------------------------------
__global__ __launch_bounds__(256)
void k_precomp(const float* __restrict__ id_embeds, const float* __restrict__ op_emb,
               const float* __restrict__ tid_emb,
               const float* __restrict__ W1, const float* __restrict__ b1,
               const float* __restrict__ Wr1, const float* __restrict__ br1,
               float* __restrict__ idW, float* __restrict__ opWb, float* __restrict__ tidWb){
  int b = blockIdx.x, tid = threadIdx.x;
  if (b < 64){
    for (int j = tid; j < 512; j += 256){
      float v = 0.f;
      #pragma unroll
      for (int u = 0; u < 4; u++) v = fmaf(id_embeds[b*4+u], W1[(size_t)(512+u)*512 + j], v);
      idW[b*512 + j] = v;
    }
  } else if (b < 67){
    int o = b - 64;
    for (int j = tid; j < 512; j += 256){
      float v = b1[j];
      for (int u = 0; u < 256; u++) v = fmaf(op_emb[o*256+u], W1[(size_t)(516+u)*512 + j], v);
      opWb[o*512 + j] = v;
    }
  } else {
    for (int idx = tid; idx < 2048; idx += 256){
      int t = idx >> 5, c = idx & 31;
      float v = br1[c];
      #pragma unroll
      for (int u = 0; u < 4; u++) v = fmaf(tid_emb[t*4+u], Wr1[(512+u)*32 + c], v);
      tidWb[idx] = v;
    }
  }
}

// ------------------------------- weight transpose + split ------------------
// W1T/W2T: 2 fp16 planes of [512][512] (k contiguous). WpT: 1 plane [8192][512].
__global__ __launch_bounds__(256)
void k_splitW(const float* __restrict__ W1, const float* __restrict__ W2,
              const float* __restrict__ Wp,
              u16* __restrict__ W1T, u16* __restrict__ W2T, u16* __restrict__ WpT){
  __shared__ float t[32][33];
  int blk = blockIdx.x;
  const float* src; u16* dst; int N; int deg; size_t pst; int tb;
  if (blk < 256){ src = W1; dst = W1T; N = 512; deg = 2; pst = (size_t)512*512; tb = blk; }
  else if (blk < 512){ src = W2; dst = W2T; N = 512; deg = 2; pst = (size_t)512*512; tb = blk - 256; }
  else { src = Wp; dst = WpT; N = 8192; deg = 1; pst = 0; tb = blk - 512; }
  int n0 = (tb >> 4)*32, k0 = (tb & 15)*32;
  int r = threadIdx.x >> 5, c = threadIdx.x & 31;
  for (int rr = r; rr < 32; rr += 8)
    t[rr][c] = src[(size_t)(k0+rr)*N + n0 + c];
  __syncthreads();
  for (int rr = r; rr < 32; rr += 8){
    float v = t[c][rr];                       // src[k0+c][n0+rr]
    size_t o = (size_t)(n0+rr)*512 + k0 + c;
    if (deg == 2){
      u16 a0, a1; split2s(v, a0, a1);
      dst[o] = a0; dst[pst + o] = a1;
    } else {
      dst[o] = f2h(v);
    }
  }
}

// ------------------------------- x -> states planes ------------------------
__global__ __launch_bounds__(256)
void k_xsplit(const float* __restrict__ x, u16* __restrict__ sP){
  size_t i = ((size_t)blockIdx.x*256 + threadIdx.x)*4;
  float4 v = *(const float4*)(x + i);
  ushort4 p0, p1;
  split2s(v.x, p0.x, p1.x); split2s(v.y, p0.y, p1.y);
  split2s(v.z, p0.z, p1.z); split2s(v.w, p0.w, p1.w);
  const size_t SP = (size_t)NPATCH*512;
  *(ushort4*)(sP + i) = p0; *(ushort4*)(sP + SP + i) = p1;
}

// ------------------------------- active compaction -------------------------
__global__ __launch_bounds__(1024)
void k_scan(const int* __restrict__ done, int* __restrict__ aidx, int* __restrict__ meta){
  __shared__ int cnt[1024];
  int tid = threadIdx.x;
  int base = tid * 32;
  unsigned flags = 0; int c = 0;
  #pragma unroll
  for (int i = 0; i < 32; i++){
    int f = (done[base + i] == 0);
    flags |= ((unsigned)f) << i;
    c += f;
  }
  cnt[tid] = c;
  __syncthreads();
  int val = c;
  for (int off = 1; off < 1024; off <<= 1){
    int v = (tid >= off) ? cnt[tid - off] : 0;
    __syncthreads();
    val += v; cnt[tid] = val;
    __syncthreads();
  }
  int pos = val - c;
  for (int i = 0; i < 32; i++){
    if ((flags >> i) & 1u) aidx[pos++] = base + i;
  }
  __syncthreads();
  int na = cnt[1023];
  for (int j = na + tid; j < NPATCH; j += 1024) aidx[j] = 0;
  if (tid == 0){
    meta[0] = na;
    meta[1] = (na < NPATCH) ? (NPATCH - 1) : 0;
  }
}

// ------------------------------- gather + op sampling ----------------------
__global__ __launch_bounds__(256)
void k_gather(const int* __restrict__ aidx, const int* __restrict__ tempers,
              const uint32_t* __restrict__ keys, const float* __restrict__ logp3,
              int hop, int* __restrict__ t_act, int* __restrict__ op_idx){
  int s = blockIdx.x*256 + threadIdx.x;
  int p = aidx[s];
  t_act[s] = tempers[p];
  uint32_t k0 = keys[2 + 4*hop], k1 = keys[3 + 4*hop];
  float best = 0.f; int bi = 0;
  #pragma unroll
  for (int c = 0; c < 3; c++){
    float v = jgumbel(jbits32(k0, k1, (uint32_t)(3*s + c))) + logp3[c];
    if (c == 0 || v > best){ best = v; bi = c; }
  }
  op_idx[s] = bi;
}

// ------------------------------- fp16x2 MFMA GEMM --------------------------
// C[M,*] = epilogue( A @ B^T ), K = 512, fp16 planes (plane1 = residual*2^12).
// DEG=2: terms a0b0 -> accM ; a0b1 + a1b0 -> accR ; v = accM + 2^-12*accR.
// DEG=1: single term.
// MODE 1: A-rows gathered via aidx, + idW[t]+opWb[op], relu, write 2 planes.
// MODE 0: + bias, relu, write fp32.   MODE 2: + bias, write fp32.
// Staging: global_load_lds 16B, global addresses XOR-swizzled so the
// lane-contiguous LDS landing yields conflict-free ds_read_b128 fragments.
template<int MODE, int DEG>
__global__ __launch_bounds__(256, 2)
void k_mgemm(const u16* __restrict__ Ap, const u16* __restrict__ Bp,
             float* __restrict__ outF, u16* __restrict__ outP,
             const int* __restrict__ aidx, const float* __restrict__ bias,
             const float* __restrict__ idW, const float* __restrict__ opWb,
             const int* __restrict__ t_act, const int* __restrict__ op_idx,
             int Ncols, size_t aStride, size_t bStride, size_t oStride){
  __shared__ u16 As[DEG*4096];   // [plane][128 rows][32 k, 16B-chunk swizzled]
  __shared__ u16 Bs[DEG*4096];
  const int tid = threadIdx.x;
  const int L = tid & 63, w = tid >> 6;
  const int m0 = blockIdx.y*128, n0 = blockIdx.x*128;
  const int wr = w >> 1, wc = w & 1;

  // waves 0,1 stage A; waves 2,3 stage B. SPW 1KB-segments per wave.
  const int SPW = DEG*4;
  const bool isA = (w < 2);
  const u16* gB = isA ? Ap : Bp;
  u16* lB = isA ? As : Bs;
  const size_t pstride = isA ? aStride : bStride;
  const u16* gseg[8];
  u16* lseg[8];
  #pragma unroll
  for (int q = 0; q < SPW; q++){
    int ss = (w & 1)*SPW + q;
    int p = ss >> 3, rb = ss & 7;
    int row16 = rb*16 + (L >> 2);
    int grow;
    if (isA) grow = (MODE == 1) ? aidx[m0 + row16] : (m0 + row16);
    else     grow = n0 + row16;
    int swz = (L & 3) ^ ((L >> 2) & 3);
    gseg[q] = gB + p*pstride + (size_t)grow*512 + swz*8;
    lseg[q] = lB + p*4096 + rb*512;        // lane L lands at +L*16B
  }

  f32x4 accM[4][4], accR[4][4];
  #pragma unroll
  for (int i = 0; i < 4; i++)
    #pragma unroll
    for (int j = 0; j < 4; j++){ accM[i][j] = (f32x4)0.f; accR[i][j] = (f32x4)0.f; }

  const int rdsw = ((L >> 4) ^ (L & 3))*8;   // swizzled 16B-chunk for reads
  const int frow = L & 15;

  for (int kt = 0; kt < 16; kt++){
    __syncthreads();
    #pragma unroll
    for (int q = 0; q < SPW; q++)
      __builtin_amdgcn_global_load_lds(
        (const __attribute__((address_space(1))) void*)(const void*)(gseg[q] + kt*32),
        (__attribute__((address_space(3))) void*)(void*)lseg[q], 16, 0, 0);
    __syncthreads();
    #pragma unroll
    for (int pa = 0; pa < DEG; pa++){
      half8 af[4];
      #pragma unroll
      for (int i = 0; i < 4; i++)
        af[i] = *(const half8*)&As[pa*4096 + (wr*64 + i*16 + frow)*32 + rdsw];
      #pragma unroll
      for (int pb = 0; pb < DEG - pa; pb++){
        #pragma unroll
        for (int j = 0; j < 4; j++){
          half8 bf = *(const half8*)&Bs[pb*4096 + (wc*64 + j*16 + frow)*32 + rdsw];
          #pragma unroll
          for (int i = 0; i < 4; i++){
            if (pa + pb == 0)
              accM[i][j] = __builtin_amdgcn_mfma_f32_16x16x32_f16(af[i], bf, accM[i][j], 0, 0, 0);
            else
              accR[i][j] = __builtin_amdgcn_mfma_f32_16x16x32_f16(af[i], bf, accR[i][j], 0, 0, 0);
          }
        }
      }
    }
  }

  // epilogue: C row = m0+wr*64+i*16+(L>>4)*4+reg, col = n0+wc*64+j*16+(L&15)
  const int rbase = m0 + wr*64 + (L >> 4)*4;
  const int cbase = n0 + wc*64 + (L & 15);
  #pragma unroll
  for (int i = 0; i < 4; i++){
    #pragma unroll
    for (int reg = 0; reg < 4; reg++){
      int r = rbase + i*16 + reg;
      if (MODE == 1){
        int t = t_act[r], o = op_idx[r];
        #pragma unroll
        for (int j = 0; j < 4; j++){
          int c = cbase + j*16;
          float v = accM[i][j][reg] + RINV*accR[i][j][reg] + idW[t*512 + c] + opWb[o*512 + c];
          v = fmaxf(v, 0.f);
          u16 a0, a1; split2s(v, a0, a1);
          size_t off = (size_t)r*512 + c;
          outP[off] = a0; outP[oStride + off] = a1;
        }
      } else {
        #pragma unroll
        for (int j = 0; j < 4; j++){
          int c = cbase + j*16;
          float v = accM[i][j][reg] + bias[c];
          if (DEG == 2) v += RINV*accR[i][j][reg];
          if (MODE == 0) v = fmaxf(v, 0.f);
          outF[(size_t)r*Ncols + c] = v;
        }
      }
    }
  }
}

// ------------------------------- routing + sample + scatter (planes) -------
__global__ __launch_bounds__(256)
void k_route2(const float* __restrict__ h2, const float* __restrict__ Wr1,
              const float* __restrict__ Wr2, const float* __restrict__ br2,
              const float* __restrict__ tidWb,
              const int* __restrict__ t_act, const int* __restrict__ aidx,
              const int* __restrict__ meta, const uint32_t* __restrict__ keys, int hop,
              u16* __restrict__ sP, int* __restrict__ tempers, int* __restrict__ done){
  __shared__ float Wr1s[256][32];
  __shared__ float h2s[8][512];
  __shared__ float l32[8][32];

  const int tid = threadIdx.x;
  const int s0 = blockIdx.x * 8;

  for (int i4 = tid; i4 < 8*128; i4 += 256){
    int sl = i4 >> 7, q = i4 & 127;
    *(float4*)&h2s[sl][q*4] = *(const float4*)&h2[(size_t)(s0+sl)*512 + q*4];
  }

  const int lane = tid & 63, w = tid >> 6;
  const int half = lane >> 5, col = lane & 31;
  const int sl = w*2 + half;
  const int s  = s0 + sl;
  const int t  = t_act[s];
  float acc = tidWb[t*32 + col];

  for (int kh = 0; kh < 2; kh++){
    __syncthreads();
    for (int idx = tid; idx < 256*32; idx += 256)
      Wr1s[idx >> 5][idx & 31] = Wr1[kh*8192 + idx];
    __syncthreads();
    const int kb = kh * 256;
    #pragma unroll 4
    for (int k4 = 0; k4 < 64; k4++){
      float4 hv = *(float4*)&h2s[sl][kb + k4*4];
      acc = fmaf(hv.x, Wr1s[k4*4+0][col], acc);
      acc = fmaf(hv.y, Wr1s[k4*4+1][col], acc);
      acc = fmaf(hv.z, Wr1s[k4*4+2][col], acc);
      acc = fmaf(hv.w, Wr1s[k4*4+3][col], acc);
    }
  }
  l32[sl][col] = fmaxf(acc, 0.f);
  __syncthreads();

  const uint32_t sk0 = keys[4 + 4*hop], sk1 = keys[5 + 4*hop];
  int smp[2];
  for (int pass = 0; pass < 2; pass++){
    const int psl = w*2 + pass;
    const int ps  = s0 + psl;
    const int c = lane;
    float lg = br2[c];
    #pragma unroll
    for (int k = 0; k < 32; k++) lg = fmaf(l32[psl][k], Wr2[k*65 + c], lg);
    float lg64 = br2[64];
    #pragma unroll
    for (int k = 0; k < 32; k++) lg64 = fmaf(l32[psl][k], Wr2[k*65 + 64], lg64);
    float m = lg;
    for (int off = 32; off; off >>= 1) m = fmaxf(m, __shfl_xor(m, off));
    m = fmaxf(m, lg64);
    float se = expf(lg - m);
    for (int off = 32; off; off >>= 1) se += __shfl_xor(se, off);
    se += expf(lg64 - m);
    float Lse = logf(se);
    float g = jgumbel(jbits32(sk0, sk1, (uint32_t)(65*ps + c)));
    float v = (lg - m) - Lse + g;
    int idx = c;
    for (int off = 32; off; off >>= 1){
      float ov = __shfl_xor(v, off);
      int   oi = __shfl_xor(idx, off);
      if (ov > v || (ov == v && oi < idx)){ v = ov; idx = oi; }
    }
    float g64 = jgumbel(jbits32(sk0, sk1, (uint32_t)(65*ps + 64)));
    float v64 = (lg64 - m) - Lse + g64;
    if (v64 > v) idx = 64;
    smp[pass] = idx;
  }

  const int mysmp = smp[half];
  const int p = aidx[s];
  const int w0v = meta[1];
  const bool allowed = (p != 0) || (s == w0v);
  if (allowed){
    const size_t SP = (size_t)NPATCH*512;
    for (int q = col; q < 128; q += 32){
      float4 v = *(float4*)&h2s[sl][q*4];
      ushort4 p0, p1;
      split2s(v.x, p0.x, p1.x); split2s(v.y, p0.y, p1.y);
      split2s(v.z, p0.z, p1.z); split2s(v.w, p0.w, p1.w);
      size_t o = (size_t)p*512 + q*4;
      *(ushort4*)(sP + o) = p0; *(ushort4*)(sP + SP + o) = p1;
    }
    if (col == 0){
      tempers[p] = (mysmp < 63) ? mysmp : 63;
      done[p]    = (mysmp == 64) ? 1 : 0;
    }
  }
}

// ------------------------------- latent (mean over patches) ----------------
__global__ __launch_bounds__(256)
void k_latent2(const u16* __restrict__ sP, float* __restrict__ outF, u16* __restrict__ latP){
  int idx = blockIdx.x*256 + threadIdx.x;       // < 2048*512
  int b = idx >> 9, j = idx & 511;
  const size_t SP = (size_t)NPATCH*512;
  float s = 0.f;
  #pragma unroll 4
  for (int u = 0; u < 16; u++){
    size_t e = (size_t)(b*16 + u)*512 + j;
    s += h2f(sP[e]) + RINV*h2f(sP[SP + e]);
  }
  s *= 0.0625f;
  outF[idx] = s;
  latP[idx] = f2h(s);
}

// ===========================================================================
// ------------- R1 fallback pipeline (fp32 VALU GEMM), verbatim -------------
// ===========================================================================
template<int MODE>
__global__ __launch_bounds__(256)
void k_gemmF(const float* __restrict__ A, const float* __restrict__ B, float* __restrict__ C,
             int Ncols,
             const int* __restrict__ aidx,
             const float* __restrict__ bias,
             const float* __restrict__ idW, const float* __restrict__ opWb,
             const int* __restrict__ t_act, const int* __restrict__ op_idx){
  __shared__ float As[16][128];
  __shared__ float Bs[16][128];
  const int tid = threadIdx.x;
  const int bx = blockIdx.x, by = blockIdx.y;
  const int tx = tid & 15, ty = tid >> 4;
  const int lr = tid >> 1, lhalf = tid & 1;
  const int srow = by*128 + lr;
  const int arow = (MODE == 1) ? aidx[srow] : srow;
  const float* Ap = A + (size_t)arow*512 + lhalf*8;
  const float* Bp = B + (size_t)(tid >> 4)*Ncols + bx*128 + (tid & 15)*8;

  float acc[8][8];
  #pragma unroll
  for (int i = 0; i < 8; i++)
    #pragma unroll
    for (int j = 0; j < 8; j++) acc[i][j] = 0.f;

  for (int kt = 0; kt < 512; kt += 16){
    float4 a0 = *(const float4*)(Ap + kt);
    float4 a1 = *(const float4*)(Ap + kt + 4);
    float4 g0 = *(const float4*)(Bp + (size_t)kt*Ncols);
    float4 g1 = *(const float4*)(Bp + (size_t)kt*Ncols + 4);
    __syncthreads();
    As[lhalf*8+0][lr] = a0.x; As[lhalf*8+1][lr] = a0.y;
    As[lhalf*8+2][lr] = a0.z; As[lhalf*8+3][lr] = a0.w;
    As[lhalf*8+4][lr] = a1.x; As[lhalf*8+5][lr] = a1.y;
    As[lhalf*8+6][lr] = a1.z; As[lhalf*8+7][lr] = a1.w;
    *(float4*)&Bs[tid>>4][(tid&15)*8]     = g0;
    *(float4*)&Bs[tid>>4][(tid&15)*8 + 4] = g1;
    __syncthreads();
    #pragma unroll
    for (int k = 0; k < 16; k++){
      float4 av0 = *(float4*)&As[k][ty*8];
      float4 av1 = *(float4*)&As[k][ty*8+4];
      float4 bv0 = *(float4*)&Bs[k][tx*4];
      float4 bv1 = *(float4*)&Bs[k][64 + tx*4];
      float av[8] = {av0.x,av0.y,av0.z,av0.w,av1.x,av1.y,av1.z,av1.w};
      float bv[8] = {bv0.x,bv0.y,bv0.z,bv0.w,bv1.x,bv1.y,bv1.z,bv1.w};
      #pragma unroll
      for (int i = 0; i < 8; i++)
        #pragma unroll
        for (int j = 0; j < 8; j++)
          acc[i][j] = fmaf(av[i], bv[j], acc[i][j]);
    }
  }

  const int col0a = bx*128 + tx*4;
  const int col0b = col0a + 64;
  #pragma unroll
  for (int i = 0; i < 8; i++){
    int s = by*128 + ty*8 + i;
    float adda[4], addb[4];
    if (MODE == 1){
      int t = t_act[s], o = op_idx[s];
      float4 ia = *(const float4*)&idW[t*512 + col0a];
      float4 ib = *(const float4*)&idW[t*512 + col0b];
      float4 oa = *(const float4*)&opWb[o*512 + col0a];
      float4 ob = *(const float4*)&opWb[o*512 + col0b];
      adda[0]=ia.x+oa.x; adda[1]=ia.y+oa.y; adda[2]=ia.z+oa.z; adda[3]=ia.w+oa.w;
      addb[0]=ib.x+ob.x; addb[1]=ib.y+ob.y; addb[2]=ib.z+ob.z; addb[3]=ib.w+ob.w;
    } else {
      float4 ba = *(const float4*)&bias[col0a];
      float4 bb = *(const float4*)&bias[col0b];
      adda[0]=ba.x; adda[1]=ba.y; adda[2]=ba.z; adda[3]=ba.w;
      addb[0]=bb.x; addb[1]=bb.y; addb[2]=bb.z; addb[3]=bb.w;
    }
    float4 va, vb;
    float* pa = &va.x; float* pb = &vb.x;
    #pragma unroll
    for (int j = 0; j < 4; j++){
      float v0 = acc[i][j]   + adda[j];
      float v1 = acc[i][j+4] + addb[j];
      if (MODE != 2){ v0 = fmaxf(v0, 0.f); v1 = fmaxf(v1, 0.f); }
      pa[j] = v0; pb[j] = v1;
    }
    *(float4*)(C + (size_t)s*Ncols + col0a) = va;
    *(float4*)(C + (size_t)s*Ncols + col0b) = vb;
  }
}

__global__ __launch_bounds__(256)
void k_routeF(const float* __restrict__ h2, const float* __restrict__ Wr1,
              const float* __restrict__ Wr2, const float* __restrict__ br2,
              const float* __restrict__ tidWb,
              const int* __restrict__ t_act, const int* __restrict__ aidx,
              const int* __restrict__ meta, const uint32_t* __restrict__ keys, int hop,
              float* __restrict__ states, int* __restrict__ tempers, int* __restrict__ done){
  __shared__ float Wr1s[256][32];
  __shared__ float h2s[8][512];
  __shared__ float l32[8][32];

  const int tid = threadIdx.x;
  const int s0 = blockIdx.x * 8;

  for (int i4 = tid; i4 < 8*128; i4 += 256){
    int sl = i4 >> 7, q = i4 & 127;
    *(float4*)&h2s[sl][q*4] = *(const float4*)&h2[(size_t)(s0+sl)*512 + q*4];
  }

  const int lane = tid & 63, w = tid >> 6;
  const int half = lane >> 5, col = lane & 31;
  const int sl = w*2 + half;
  const int s  = s0 + sl;
  const int t  = t_act[s];
  float acc = tidWb[t*32 + col];

  for (int kh = 0; kh < 2; kh++){
    __syncthreads();
    for (int idx = tid; idx < 256*32; idx += 256)
      Wr1s[idx >> 5][idx & 31] = Wr1[kh*8192 + idx];
    __syncthreads();
    const int kb = kh * 256;
    #pragma unroll 4
    for (int k4 = 0; k4 < 64; k4++){
      float4 hv = *(float4*)&h2s[sl][kb + k4*4];
      acc = fmaf(hv.x, Wr1s[k4*4+0][col], acc);
      acc = fmaf(hv.y, Wr1s[k4*4+1][col], acc);
      acc = fmaf(hv.z, Wr1s[k4*4+2][col], acc);
      acc = fmaf(hv.w, Wr1s[k4*4+3][col], acc);
    }
  }
  l32[sl][col] = fmaxf(acc, 0.f);
  __syncthreads();

  const uint32_t sk0 = keys[4 + 4*hop], sk1 = keys[5 + 4*hop];
  int smp[2];
  for (int pass = 0; pass < 2; pass++){
    const int psl = w*2 + pass;
    const int ps  = s0 + psl;
    const int c = lane;
    float lg = br2[c];
    #pragma unroll
    for (int k = 0; k < 32; k++) lg = fmaf(l32[psl][k], Wr2[k*65 + c], lg);
    float lg64 = br2[64];
    #pragma unroll
    for (int k = 0; k < 32; k++) lg64 = fmaf(l32[psl][k], Wr2[k*65 + 64], lg64);
    float m = lg;
    for (int off = 32; off; off >>= 1) m = fmaxf(m, __shfl_xor(m, off));
    m = fmaxf(m, lg64);
    float se = expf(lg - m);
    for (int off = 32; off; off >>= 1) se += __shfl_xor(se, off);
    se += expf(lg64 - m);
    float Lse = logf(se);
    float g = jgumbel(jbits32(sk0, sk1, (uint32_t)(65*ps + c)));
    float v = (lg - m) - Lse + g;
    int idx = c;
    for (int off = 32; off; off >>= 1){
      float ov = __shfl_xor(v, off);
      int   oi = __shfl_xor(idx, off);
      if (ov > v || (ov == v && oi < idx)){ v = ov; idx = oi; }
    }
    float g64 = jgumbel(jbits32(sk0, sk1, (uint32_t)(65*ps + 64)));
    float v64 = (lg64 - m) - Lse + g64;
    if (v64 > v) idx = 64;
    smp[pass] = idx;
  }

  const int mysmp = smp[half];
  const int p = aidx[s];
  const int w0v = meta[1];
  const bool allowed = (p != 0) || (s == w0v);
  if (allowed){
    const float4* src = (const float4*)&h2s[sl][0];
    float4* dst = (float4*)(states + (size_t)p*512);
    for (int q = col; q < 128; q += 32) dst[q] = src[q];
    if (col == 0){
      tempers[p] = (mysmp < 63) ? mysmp : 63;
      done[p]    = (mysmp == 64) ? 1 : 0;
    }
  }
}

__global__ __launch_bounds__(256)
void k_latentF(const float* __restrict__ states, float* __restrict__ out){
  int idx = blockIdx.x*256 + threadIdx.x;
  int b = idx >> 9, j = idx & 511;
  float s = 0.f;
  #pragma unroll
  for (int u = 0; u < 16; u++) s += states[(size_t)(b*16 + u)*512 + j];
  out[idx] = s * 0.0625f;
}

// ------------------------------- launch ------------------------------------
extern "C" void kernel_launch(void* const* d_in, const int* in_sizes, int n_in,
                              void* d_out, int out_size, void* d_ws, size_t ws_size,
                              hipStream_t stream) {
  (void)in_sizes; (void)n_in; (void)out_size;
  const float* x         = (const float*)d_in[0];
  const float* op_emb    = (const float*)d_in[1];
  const float* op_logits = (const float*)d_in[2];
  const float* id_embeds = (const float*)d_in[3];
  const float* W1        = (const float*)d_in[4];
  const float* b1        = (const float*)d_in[5];
  const float* W2        = (const float*)d_in[6];
  const float* b2        = (const float*)d_in[7];
  const float* Wr1       = (const float*)d_in[8];
  const float* br1       = (const float*)d_in[9];
  const float* Wr2       = (const float*)d_in[10];
  const float* br2       = (const float*)d_in[11];
  const float* Wp        = (const float*)d_in[12];
  const float* bp        = (const float*)d_in[13];
  const float* tid_emb   = (const float*)d_in[14];
  const int*   seed      = (const int*)d_in[15];
  float* out = (float*)d_out;

  char* w = (char*)d_ws;
  uint32_t* keys = (uint32_t*)w;                 // @0
  float* logp3   = (float*)(w + 256);
  int*   meta    = (int*)(w + 512);
  int*   tempers = (int*)(w + 4096);
  int*   done    = tempers + NPATCH;
  int*   t_act   = done + NPATCH;
  int*   op_idx  = t_act + NPATCH;
  int*   aidx    = op_idx + NPATCH;
  float* idW     = (float*)(aidx + NPATCH);
  float* opWb    = idW + 64*512;
  float* tidWb   = opWb + 3*512;                 // ends < 1 MB

  const size_t SPh = (size_t)NPATCH*512;         // per-plane elems for states/h1
  u16* W1T     = (u16*)(w + (1u<<20));           // 2 planes 512x512
  u16* W2T     = W1T + (size_t)2*512*512;        // 2 planes 512x512
  u16* WpT     = W2T + (size_t)2*512*512;        // 1 plane 8192x512
  u16* latP    = WpT + (size_t)8192*512;         // 1 plane 2048x512
  u16* statesP = latP + (size_t)2048*512;        // 2 planes
  u16* h1P     = statesP + 2*SPh;                // 2 planes
  float* h2W   = (float*)(h1P + 2*SPh);          // fp32
  const size_t NEED1 = (size_t)((char*)(h2W) - w);
  const size_t NEED2 = NEED1 + SPh*sizeof(float);

  k_keys<<<1, 64, 0, stream>>>(seed, op_logits, keys, logp3);
  k_init<<<NPATCH/256, 256, 0, stream>>>(keys, tempers, done);
  k_precomp<<<68, 256, 0, stream>>>(id_embeds, op_emb, tid_emb, W1, b1, Wr1, br1,
                                    idW, opWb, tidWb);

  if (ws_size >= NEED2){
    // ---------------- fp16x2 MFMA path ----------------
    float* h2 = h2W;
    k_splitW<<<4608, 256, 0, stream>>>(W1, W2, Wp, W1T, W2T, WpT);
    k_xsplit<<<(NPATCH*512/4)/256, 256, 0, stream>>>(x, statesP);

    for (int hop = 0; hop < NHOP; hop++){
      k_scan<<<1, 1024, 0, stream>>>(done, aidx, meta);
      k_gather<<<NPATCH/256, 256, 0, stream>>>(aidx, tempers, keys, logp3, hop, t_act, op_idx);
      k_mgemm<1,2><<<dim3(4, NPATCH/128), 256, 0, stream>>>(
          statesP, W1T, nullptr, h1P, aidx, nullptr, idW, opWb, t_act, op_idx,
          512, SPh, (size_t)512*512, SPh);
      k_mgemm<0,2><<<dim3(4, NPATCH/128), 256, 0, stream>>>(
          h1P, W2T, h2, nullptr, nullptr, b2, nullptr, nullptr, nullptr, nullptr,
          512, SPh, (size_t)512*512, 0);
      k_route2<<<NPATCH/8, 256, 0, stream>>>(h2, Wr1, Wr2, br2, tidWb, t_act, aidx,
                                             meta, keys, hop, statesP, tempers, done);
    }

    k_latent2<<<(2048*512)/256, 256, 0, stream>>>(statesP, out, latP);
    k_mgemm<2,1><<<dim3(64, 16), 256, 0, stream>>>(
        latP, WpT, out + 2048*512, nullptr, nullptr, bp, nullptr, nullptr, nullptr, nullptr,
        8192, (size_t)2048*512, (size_t)8192*512, 0);
  } else {
    // ---------------- R1 fp32 fallback ----------------
    const size_t BIG0 = 2u<<20;
    const size_t SB   = (size_t)NPATCH * 512 * sizeof(float);
    float *states, *h1, *h2;
    bool copy_states;
    if (ws_size >= BIG0 + 3*SB){
      states = (float*)(w + BIG0);
      h1     = (float*)(w + BIG0 + SB);
      h2     = (float*)(w + BIG0 + 2*SB);
      copy_states = true;
    } else {
      states = (float*)d_in[0];
      h1     = (float*)(w + BIG0);
      h2     = (float*)(w + BIG0 + SB);
      copy_states = false;
    }
    if (copy_states)
      hipMemcpyAsync(states, x, SB, hipMemcpyDeviceToDevice, stream);

    for (int hop = 0; hop < NHOP; hop++){
      k_scan<<<1, 1024, 0, stream>>>(done, aidx, meta);
      k_gather<<<NPATCH/256, 256, 0, stream>>>(aidx, tempers, keys, logp3, hop, t_act, op_idx);
      k_gemmF<1><<<dim3(4, NPATCH/128), 256, 0, stream>>>(states, W1, h1, 512,
                                      aidx, nullptr, idW, opWb, t_act, op_idx);
      k_gemmF<0><<<dim3(4, NPATCH/128), 256, 0, stream>>>(h1, W2, h2, 512,
                                      nullptr, b2, nullptr, nullptr, nullptr, nullptr);
      k_routeF<<<NPATCH/8, 256, 0, stream>>>(h2, Wr1, Wr2, br2, tidWb, t_act, aidx,
                                      meta, keys, hop, states, tempers, done);
    }

    k_latentF<<<(2048*512)/256, 256, 0, stream>>>(states, out);
    k_gemmF<2><<<dim3(8192/128, 2048/128), 256, 0, stream>>>(out, Wp, out + 2048*512, 8192,
                                      nullptr, bp, nullptr, nullptr, nullptr, nullptr);
  }
}

// Round 4
// 1072.099 us; speedup vs baseline: 2.1415x; 1.1288x over previous
//
#include <hip/hip_runtime.h>
#include <cstdint>
#include <cstddef>

// ---------------------------------------------------------------------------
// TemperGraph on gfx950 — R4: R3's fp16x2 MFMA GEMMs kept; k_route2 split:
//   GEMM2 epilogue scatters h directly into statesP[aidx[s]] (masked),
//   k_routemm = small-N MFMA GEMM for l32, k_sample = sampling only.
// Exact JAX threefry sampling preserved (passed R1-R3).
// ---------------------------------------------------------------------------

#define NPATCH 32768          // B(2048) * num_patches(16)
#define NHOP 4
#define RSCALE 4096.0f
#define RINV   2.44140625e-4f  // 2^-12

typedef unsigned short u16;
typedef __attribute__((ext_vector_type(8))) _Float16 half8;  // 8 f16 (4 VGPRs)
typedef __attribute__((ext_vector_type(4))) float f32x4;

#define GLDS(gp, lp) __builtin_amdgcn_global_load_lds( \
    (const __attribute__((address_space(1))) void*)(const void*)(gp), \
    (__attribute__((address_space(3))) void*)(void*)(lp), 16, 0, 0)

// ------------------------------- threefry ----------------------------------
__device__ __forceinline__ uint32_t rotl32(uint32_t x, int r){ return (x<<r)|(x>>(32-r)); }

__device__ __forceinline__ void tf2x32(uint32_t k0, uint32_t k1, uint32_t x0, uint32_t x1,
                                       uint32_t& o0, uint32_t& o1){
  uint32_t k2 = k0 ^ k1 ^ 0x1BD11BDAu;
  x0 += k0; x1 += k1;
#define TFR(r) { x0 += x1; x1 = rotl32(x1,(r)); x1 ^= x0; }
  TFR(13) TFR(15) TFR(26) TFR(6)   x0 += k1; x1 += k2 + 1u;
  TFR(17) TFR(29) TFR(16) TFR(24)  x0 += k2; x1 += k0 + 2u;
  TFR(13) TFR(15) TFR(26) TFR(6)   x0 += k0; x1 += k1 + 3u;
  TFR(17) TFR(29) TFR(16) TFR(24)  x0 += k1; x1 += k2 + 4u;
  TFR(13) TFR(15) TFR(26) TFR(6)   x0 += k2; x1 += k0 + 5u;
#undef TFR
  o0 = x0; o1 = x1;
}

__device__ __forceinline__ uint32_t jbits32(uint32_t k0, uint32_t k1, uint32_t idx){
  uint32_t a, b; tf2x32(k0, k1, 0u, idx, a, b);
  return a ^ b;
}

__device__ __forceinline__ void jsplit(uint32_t& r0, uint32_t& r1, uint32_t& c0, uint32_t& c1){
  uint32_t n0, n1;
  tf2x32(r0, r1, 0u, 0u, n0, n1);
  tf2x32(r0, r1, 0u, 1u, c0, c1);
  r0 = n0; r1 = n1;
}

__device__ __forceinline__ float jgumbel(uint32_t bits){
  float f = __uint_as_float(0x3f800000u | (bits >> 9)) - 1.0f;
  float u = fmaxf(f, 1.17549435e-38f);
  return -logf(-logf(u));
}

// ------------------------------- fp16 split helpers ------------------------
union uhcv { _Float16 h; u16 u; };
__device__ __forceinline__ u16 f2h(float x){ uhcv t; t.h = (_Float16)x; return t.u; }
__device__ __forceinline__ float h2f(u16 b){ uhcv t; t.u = b; return (float)t.h; }
__device__ __forceinline__ void split2s(float v, u16& a0, u16& a1){
  a0 = f2h(v);
  a1 = f2h((v - h2f(a0)) * RSCALE);
}

// ------------------------------- key derivation ----------------------------
__global__ void k_keys(const int* __restrict__ seed, const float* __restrict__ op_logits,
                       uint32_t* __restrict__ keys, float* __restrict__ logp3){
  if (threadIdx.x != 0 || blockIdx.x != 0) return;
  uint32_t r0 = 0u, r1 = (uint32_t)seed[0];
  uint32_t c0, c1;
  jsplit(r0, r1, c0, c1); keys[0] = c0; keys[1] = c1;          // tk
  for (int h = 0; h < NHOP; h++){
    jsplit(r0, r1, c0, c1); keys[2 + 4*h] = c0; keys[3 + 4*h] = c1;  // ok_h
    jsplit(r0, r1, c0, c1); keys[4 + 4*h] = c0; keys[5 + 4*h] = c1;  // sk_h
  }
  float l0 = op_logits[0], l1 = op_logits[1], l2 = op_logits[2];
  float mm = fmaxf(l0, fmaxf(l1, l2));
  float e0 = expf(l0-mm), e1 = expf(l1-mm), e2 = expf(l2-mm);
  float ssum = e0 + e1 + e2;
  logp3[0] = logf(e0/ssum); logp3[1] = logf(e1/ssum); logp3[2] = logf(e2/ssum);
}

// ------------------------------- init --------------------------------------
__global__ __launch_bounds__(256)
void k_init(const uint32_t* __restrict__ keys, int* __restrict__ tempers, int* __restrict__ done){
  int i = blockIdx.x*256 + threadIdx.x;
  uint32_t b = jbits32(keys[0], keys[1], (uint32_t)(NPATCH + i));
  tempers[i] = (int)(b & 63u);
  done[i] = 0;
}

// ------------------------------- precompute --------------------------------
__global__ __launch_bounds__(256)
void k_precomp(const float* __restrict__ id_embeds, const float* __restrict__ op_emb,
               const float* __restrict__ tid_emb,
               const float* __restrict__ W1, const float* __restrict__ b1,
               const float* __restrict__ Wr1, const float* __restrict__ br1,
               float* __restrict__ idW, float* __restrict__ opWb, float* __restrict__ tidWb){
  int b = blockIdx.x, tid = threadIdx.x;
  if (b < 64){
    for (int j = tid; j < 512; j += 256){
      float v = 0.f;
      #pragma unroll
      for (int u = 0; u < 4; u++) v = fmaf(id_embeds[b*4+u], W1[(size_t)(512+u)*512 + j], v);
      idW[b*512 + j] = v;
    }
  } else if (b < 67){
    int o = b - 64;
    for (int j = tid; j < 512; j += 256){
      float v = b1[j];
      for (int u = 0; u < 256; u++) v = fmaf(op_emb[o*256+u], W1[(size_t)(516+u)*512 + j], v);
      opWb[o*512 + j] = v;
    }
  } else {
    for (int idx = tid; idx < 2048; idx += 256){
      int t = idx >> 5, c = idx & 31;
      float v = br1[c];
      #pragma unroll
      for (int u = 0; u < 4; u++) v = fmaf(tid_emb[t*4+u], Wr1[(512+u)*32 + c], v);
      tidWb[idx] = v;
    }
  }
}

// ------------------------------- weight transpose + split ------------------
// W1T/W2T: 2 fp16 planes [512][512] (k contig). Wr1P: 2 planes [32][512].
// WpT: 1 plane [8192][512].
__global__ __launch_bounds__(256)
void k_splitW(const float* __restrict__ W1, const float* __restrict__ W2,
              const float* __restrict__ Wp, const float* __restrict__ Wr1,
              u16* __restrict__ W1T, u16* __restrict__ W2T, u16* __restrict__ WpT,
              u16* __restrict__ Wr1P){
  __shared__ float t[32][33];
  int blk = blockIdx.x;
  const float* src; u16* dst; int N; int deg; size_t pst; int tb;
  if (blk < 256){ src = W1; dst = W1T; N = 512; deg = 2; pst = (size_t)512*512; tb = blk; }
  else if (blk < 512){ src = W2; dst = W2T; N = 512; deg = 2; pst = (size_t)512*512; tb = blk - 256; }
  else if (blk < 528){ src = Wr1; dst = Wr1P; N = 32; deg = 2; pst = (size_t)32*512; tb = blk - 512; }
  else { src = Wp; dst = WpT; N = 8192; deg = 1; pst = 0; tb = blk - 528; }
  int n0 = (tb >> 4)*32, k0 = (tb & 15)*32;
  if (N == 32){ n0 = 0; k0 = tb*32; }
  int r = threadIdx.x >> 5, c = threadIdx.x & 31;
  for (int rr = r; rr < 32; rr += 8)
    t[rr][c] = src[(size_t)(k0+rr)*N + ((n0 + c) % N)];
  __syncthreads();
  for (int rr = r; rr < 32; rr += 8){
    if (n0 + rr >= N) break;
    float v = t[c][rr];                       // src[k0+c][n0+rr]
    size_t o = (size_t)(n0+rr)*512 + k0 + c;
    if (deg == 2){
      u16 a0, a1; split2s(v, a0, a1);
      dst[o] = a0; dst[pst + o] = a1;
    } else {
      dst[o] = f2h(v);
    }
  }
}

// ------------------------------- x -> states planes ------------------------
__global__ __launch_bounds__(256)
void k_xsplit(const float* __restrict__ x, u16* __restrict__ sP){
  size_t i = ((size_t)blockIdx.x*256 + threadIdx.x)*4;
  float4 v = *(const float4*)(x + i);
  ushort4 p0, p1;
  split2s(v.x, p0.x, p1.x); split2s(v.y, p0.y, p1.y);
  split2s(v.z, p0.z, p1.z); split2s(v.w, p0.w, p1.w);
  const size_t SP = (size_t)NPATCH*512;
  *(ushort4*)(sP + i) = p0; *(ushort4*)(sP + SP + i) = p1;
}

// ------------------------------- active compaction -------------------------
__global__ __launch_bounds__(1024)
void k_scan(const int* __restrict__ done, int* __restrict__ aidx, int* __restrict__ meta){
  __shared__ int cnt[1024];
  int tid = threadIdx.x;
  int base = tid * 32;
  unsigned flags = 0; int c = 0;
  #pragma unroll
  for (int i = 0; i < 32; i++){
    int f = (done[base + i] == 0);
    flags |= ((unsigned)f) << i;
    c += f;
  }
  cnt[tid] = c;
  __syncthreads();
  int val = c;
  for (int off = 1; off < 1024; off <<= 1){
    int v = (tid >= off) ? cnt[tid - off] : 0;
    __syncthreads();
    val += v; cnt[tid] = val;
    __syncthreads();
  }
  int pos = val - c;
  for (int i = 0; i < 32; i++){
    if ((flags >> i) & 1u) aidx[pos++] = base + i;
  }
  __syncthreads();
  int na = cnt[1023];
  for (int j = na + tid; j < NPATCH; j += 1024) aidx[j] = 0;
  if (tid == 0){
    meta[0] = na;
    meta[1] = (na < NPATCH) ? (NPATCH - 1) : 0;
  }
}

// ------------------------------- gather + op sampling ----------------------
__global__ __launch_bounds__(256)
void k_gather(const int* __restrict__ aidx, const int* __restrict__ tempers,
              const uint32_t* __restrict__ keys, const float* __restrict__ logp3,
              int hop, int* __restrict__ t_act, int* __restrict__ op_idx){
  int s = blockIdx.x*256 + threadIdx.x;
  int p = aidx[s];
  t_act[s] = tempers[p];
  uint32_t k0 = keys[2 + 4*hop], k1 = keys[3 + 4*hop];
  float best = 0.f; int bi = 0;
  #pragma unroll
  for (int c = 0; c < 3; c++){
    float v = jgumbel(jbits32(k0, k1, (uint32_t)(3*s + c))) + logp3[c];
    if (c == 0 || v > best){ best = v; bi = c; }
  }
  op_idx[s] = bi;
}

// ------------------------------- fp16x2 MFMA GEMM --------------------------
// MODE 1: A gathered via aidx, + idW[t]+opWb[op], relu, write 2 planes (by s).
// MODE 3: + bias, relu, SCATTER 2 planes to outP[aidx[r]] masked last-wins.
// MODE 2: + bias, write fp32 (DEG=1).
template<int MODE, int DEG>
__global__ __launch_bounds__(256, 2)
void k_mgemm(const u16* __restrict__ Ap, const u16* __restrict__ Bp,
             float* __restrict__ outF, u16* __restrict__ outP,
             const int* __restrict__ aidx, const float* __restrict__ bias,
             const float* __restrict__ idW, const float* __restrict__ opWb,
             const int* __restrict__ t_act, const int* __restrict__ op_idx,
             const int* __restrict__ meta,
             int Ncols, size_t aStride, size_t bStride, size_t oStride){
  __shared__ u16 As[DEG*4096];   // [plane][128 rows][32 k, 16B-chunk swizzled]
  __shared__ u16 Bs[DEG*4096];
  const int tid = threadIdx.x;
  const int L = tid & 63, w = tid >> 6;
  const int m0 = blockIdx.y*128, n0 = blockIdx.x*128;
  const int wr = w >> 1, wc = w & 1;

  const int SPW = DEG*4;
  const bool isA = (w < 2);
  const u16* gB = isA ? Ap : Bp;
  u16* lB = isA ? As : Bs;
  const size_t pstride = isA ? aStride : bStride;
  const u16* gseg[8];
  u16* lseg[8];
  #pragma unroll
  for (int q = 0; q < SPW; q++){
    int ss = (w & 1)*SPW + q;
    int p = ss >> 3, rb = ss & 7;
    int row16 = rb*16 + (L >> 2);
    int grow;
    if (isA) grow = (MODE == 1) ? aidx[m0 + row16] : (m0 + row16);
    else     grow = n0 + row16;
    int swz = (L & 3) ^ ((L >> 2) & 3);
    gseg[q] = gB + p*pstride + (size_t)grow*512 + swz*8;
    lseg[q] = lB + p*4096 + rb*512;
  }

  f32x4 accM[4][4], accR[4][4];
  #pragma unroll
  for (int i = 0; i < 4; i++)
    #pragma unroll
    for (int j = 0; j < 4; j++){ accM[i][j] = (f32x4)0.f; accR[i][j] = (f32x4)0.f; }

  const int rdsw = ((L >> 4) ^ (L & 3))*8;
  const int frow = L & 15;

  for (int kt = 0; kt < 16; kt++){
    __syncthreads();
    #pragma unroll
    for (int q = 0; q < SPW; q++)
      GLDS(gseg[q] + kt*32, lseg[q]);
    __syncthreads();
    #pragma unroll
    for (int pa = 0; pa < DEG; pa++){
      half8 af[4];
      #pragma unroll
      for (int i = 0; i < 4; i++)
        af[i] = *(const half8*)&As[pa*4096 + (wr*64 + i*16 + frow)*32 + rdsw];
      #pragma unroll
      for (int pb = 0; pb < DEG - pa; pb++){
        #pragma unroll
        for (int j = 0; j < 4; j++){
          half8 bf = *(const half8*)&Bs[pb*4096 + (wc*64 + j*16 + frow)*32 + rdsw];
          #pragma unroll
          for (int i = 0; i < 4; i++){
            if (pa + pb == 0)
              accM[i][j] = __builtin_amdgcn_mfma_f32_16x16x32_f16(af[i], bf, accM[i][j], 0, 0, 0);
            else
              accR[i][j] = __builtin_amdgcn_mfma_f32_16x16x32_f16(af[i], bf, accR[i][j], 0, 0, 0);
          }
        }
      }
    }
  }

  const int rbase = m0 + wr*64 + (L >> 4)*4;
  const int cbase = n0 + wc*64 + (L & 15);
  const int w0v = (MODE == 3) ? meta[1] : 0;
  #pragma unroll
  for (int i = 0; i < 4; i++){
    #pragma unroll
    for (int reg = 0; reg < 4; reg++){
      int r = rbase + i*16 + reg;
      if (MODE == 1){
        int t = t_act[r], o = op_idx[r];
        #pragma unroll
        for (int j = 0; j < 4; j++){
          int c = cbase + j*16;
          float v = accM[i][j][reg] + RINV*accR[i][j][reg] + idW[t*512 + c] + opWb[o*512 + c];
          v = fmaxf(v, 0.f);
          u16 a0, a1; split2s(v, a0, a1);
          size_t off = (size_t)r*512 + c;
          outP[off] = a0; outP[oStride + off] = a1;
        }
      } else if (MODE == 3){
        int p = aidx[r];
        bool allowed = (p != 0) || (r == w0v);
        #pragma unroll
        for (int j = 0; j < 4; j++){
          int c = cbase + j*16;
          float v = accM[i][j][reg] + RINV*accR[i][j][reg] + bias[c];
          v = fmaxf(v, 0.f);
          if (allowed){
            u16 a0, a1; split2s(v, a0, a1);
            size_t off = (size_t)p*512 + c;
            outP[off] = a0; outP[oStride + off] = a1;
          }
        }
      } else {
        #pragma unroll
        for (int j = 0; j < 4; j++){
          int c = cbase + j*16;
          float v = accM[i][j][reg] + bias[c];
          if (DEG == 2) v += RINV*accR[i][j][reg];
          outF[(size_t)r*Ncols + c] = v;
        }
      }
    }
  }
}

// ------------------------------- routing matvec via MFMA -------------------
// l32[s][c] = relu( statesP[aidx[s]] . Wr1P[c] + tidWb[t_act[s]][c] )
// 64 rows/block, 4 waves x 16 rows; fp16x2 3-term.
__global__ __launch_bounds__(256, 2)
void k_routemm(const u16* __restrict__ sP, const u16* __restrict__ Wr1P,
               const int* __restrict__ aidx, const int* __restrict__ t_act,
               const float* __restrict__ tidWb, float* __restrict__ l32g){
  __shared__ u16 As[2*2048];     // [plane][64 rows][32 k swizzled]
  __shared__ u16 Bs[2048];       // [p][ct][q4][nn][8]
  const int tid = threadIdx.x;
  const int L = tid & 63, w = tid >> 6;
  const int m0 = blockIdx.x*64;
  const size_t SPh = (size_t)NPATCH*512;

  const u16* gseg[2]; u16* lseg[2];
  #pragma unroll
  for (int q = 0; q < 2; q++){
    int ss = w*2 + q;
    int p = ss >> 2, rb = ss & 3;
    int row16 = rb*16 + (L >> 2);
    int grow = aidx[m0 + row16];
    int swz = (L & 3) ^ ((L >> 2) & 3);
    gseg[q] = sP + p*SPh + (size_t)grow*512 + swz*8;
    lseg[q] = As + p*2048 + rb*512;
  }
  const u16* gBp = Wr1P + (size_t)(tid>>7)*16384
                        + (size_t)(((tid>>6)&1)*16 + (tid&15))*512 + ((tid>>4)&3)*8;
  u16* lBp = Bs + w*512;

  f32x4 accM[2], accR[2];
  accM[0] = (f32x4)0.f; accM[1] = (f32x4)0.f;
  accR[0] = (f32x4)0.f; accR[1] = (f32x4)0.f;

  const int rdsw = ((L >> 4) ^ (L & 3))*8;
  for (int kt = 0; kt < 16; kt++){
    __syncthreads();
    #pragma unroll
    for (int q = 0; q < 2; q++)
      GLDS(gseg[q] + kt*32, lseg[q]);
    GLDS(gBp + kt*32, lBp);
    __syncthreads();
    #pragma unroll
    for (int pa = 0; pa < 2; pa++){
      half8 af = *(const half8*)&As[pa*2048 + (w*16 + (L & 15))*32 + rdsw];
      #pragma unroll
      for (int pb = 0; pb < 2 - pa; pb++){
        #pragma unroll
        for (int ct = 0; ct < 2; ct++){
          half8 bf = *(const half8*)&Bs[(pb*2 + ct)*512 + (L >> 4)*128 + (L & 15)*8];
          if (pa + pb == 0)
            accM[ct] = __builtin_amdgcn_mfma_f32_16x16x32_f16(af, bf, accM[ct], 0, 0, 0);
          else
            accR[ct] = __builtin_amdgcn_mfma_f32_16x16x32_f16(af, bf, accR[ct], 0, 0, 0);
        }
      }
    }
  }

  #pragma unroll
  for (int reg = 0; reg < 4; reg++){
    int s = m0 + w*16 + (L >> 4)*4 + reg;
    int t = t_act[s];
    #pragma unroll
    for (int ct = 0; ct < 2; ct++){
      int c = ct*16 + (L & 15);
      float v = accM[ct][reg] + RINV*accR[ct][reg] + tidWb[t*32 + c];
      l32g[(size_t)s*32 + c] = fmaxf(v, 0.f);
    }
  }
}

// ------------------------------- sampling ----------------------------------
__global__ __launch_bounds__(256)
void k_sample(const float* __restrict__ l32g, const float* __restrict__ Wr2,
              const float* __restrict__ br2,
              const int* __restrict__ aidx, const int* __restrict__ meta,
              const uint32_t* __restrict__ keys, int hop,
              int* __restrict__ tempers, int* __restrict__ done){
  __shared__ float l32s[8][32];
  const int tid = threadIdx.x;
  const int s0 = blockIdx.x * 8;
  l32s[tid >> 5][tid & 31] = l32g[(size_t)s0*32 + tid];
  __syncthreads();

  const int lane = tid & 63, w = tid >> 6;
  const int half = lane >> 5;
  const uint32_t sk0 = keys[4 + 4*hop], sk1 = keys[5 + 4*hop];
  int smp[2];
  for (int pass = 0; pass < 2; pass++){
    const int psl = w*2 + pass;
    const int ps  = s0 + psl;
    const int c = lane;
    float lg = br2[c];
    #pragma unroll
    for (int k = 0; k < 32; k++) lg = fmaf(l32s[psl][k], Wr2[k*65 + c], lg);
    float lg64 = br2[64];
    #pragma unroll
    for (int k = 0; k < 32; k++) lg64 = fmaf(l32s[psl][k], Wr2[k*65 + 64], lg64);
    float m = lg;
    for (int off = 32; off; off >>= 1) m = fmaxf(m, __shfl_xor(m, off));
    m = fmaxf(m, lg64);
    float se = expf(lg - m);
    for (int off = 32; off; off >>= 1) se += __shfl_xor(se, off);
    se += expf(lg64 - m);
    float Lse = logf(se);
    float g = jgumbel(jbits32(sk0, sk1, (uint32_t)(65*ps + c)));
    float v = (lg - m) - Lse + g;
    int idx = c;
    for (int off = 32; off; off >>= 1){
      float ov = __shfl_xor(v, off);
      int   oi = __shfl_xor(idx, off);
      if (ov > v || (ov == v && oi < idx)){ v = ov; idx = oi; }
    }
    float g64 = jgumbel(jbits32(sk0, sk1, (uint32_t)(65*ps + 64)));
    float v64 = (lg64 - m) - Lse + g64;
    if (v64 > v) idx = 64;
    smp[pass] = idx;
  }

  const int s = s0 + w*2 + half;
  const int mysmp = smp[half];
  const int p = aidx[s];
  const bool allowed = (p != 0) || (s == meta[1]);
  if (allowed && (lane & 31) == 0){
    tempers[p] = (mysmp < 63) ? mysmp : 63;
    done[p]    = (mysmp == 64) ? 1 : 0;
  }
}

// ------------------------------- latent (mean over patches) ----------------
__global__ __launch_bounds__(256)
void k_latent2(const u16* __restrict__ sP, float* __restrict__ outF, u16* __restrict__ latP){
  int idx = blockIdx.x*256 + threadIdx.x;       // < 2048*512
  int b = idx >> 9, j = idx & 511;
  const size_t SP = (size_t)NPATCH*512;
  float s = 0.f;
  #pragma unroll 4
  for (int u = 0; u < 16; u++){
    size_t e = (size_t)(b*16 + u)*512 + j;
    s += h2f(sP[e]) + RINV*h2f(sP[SP + e]);
  }
  s *= 0.0625f;
  outF[idx] = s;
  latP[idx] = f2h(s);
}

// ===========================================================================
// ------------- R1 fallback pipeline (fp32 VALU GEMM), verbatim -------------
// ===========================================================================
template<int MODE>
__global__ __launch_bounds__(256)
void k_gemmF(const float* __restrict__ A, const float* __restrict__ B, float* __restrict__ C,
             int Ncols,
             const int* __restrict__ aidx,
             const float* __restrict__ bias,
             const float* __restrict__ idW, const float* __restrict__ opWb,
             const int* __restrict__ t_act, const int* __restrict__ op_idx){
  __shared__ float As[16][128];
  __shared__ float Bs[16][128];
  const int tid = threadIdx.x;
  const int bx = blockIdx.x, by = blockIdx.y;
  const int tx = tid & 15, ty = tid >> 4;
  const int lr = tid >> 1, lhalf = tid & 1;
  const int srow = by*128 + lr;
  const int arow = (MODE == 1) ? aidx[srow] : srow;
  const float* Ap = A + (size_t)arow*512 + lhalf*8;
  const float* Bp = B + (size_t)(tid >> 4)*Ncols + bx*128 + (tid & 15)*8;

  float acc[8][8];
  #pragma unroll
  for (int i = 0; i < 8; i++)
    #pragma unroll
    for (int j = 0; j < 8; j++) acc[i][j] = 0.f;

  for (int kt = 0; kt < 512; kt += 16){
    float4 a0 = *(const float4*)(Ap + kt);
    float4 a1 = *(const float4*)(Ap + kt + 4);
    float4 g0 = *(const float4*)(Bp + (size_t)kt*Ncols);
    float4 g1 = *(const float4*)(Bp + (size_t)kt*Ncols + 4);
    __syncthreads();
    As[lhalf*8+0][lr] = a0.x; As[lhalf*8+1][lr] = a0.y;
    As[lhalf*8+2][lr] = a0.z; As[lhalf*8+3][lr] = a0.w;
    As[lhalf*8+4][lr] = a1.x; As[lhalf*8+5][lr] = a1.y;
    As[lhalf*8+6][lr] = a1.z; As[lhalf*8+7][lr] = a1.w;
    *(float4*)&Bs[tid>>4][(tid&15)*8]     = g0;
    *(float4*)&Bs[tid>>4][(tid&15)*8 + 4] = g1;
    __syncthreads();
    #pragma unroll
    for (int k = 0; k < 16; k++){
      float4 av0 = *(float4*)&As[k][ty*8];
      float4 av1 = *(float4*)&As[k][ty*8+4];
      float4 bv0 = *(float4*)&Bs[k][tx*4];
      float4 bv1 = *(float4*)&Bs[k][64 + tx*4];
      float av[8] = {av0.x,av0.y,av0.z,av0.w,av1.x,av1.y,av1.z,av1.w};
      float bv[8] = {bv0.x,bv0.y,bv0.z,bv0.w,bv1.x,bv1.y,bv1.z,bv1.w};
      #pragma unroll
      for (int i = 0; i < 8; i++)
        #pragma unroll
        for (int j = 0; j < 8; j++)
          acc[i][j] = fmaf(av[i], bv[j], acc[i][j]);
    }
  }

  const int col0a = bx*128 + tx*4;
  const int col0b = col0a + 64;
  #pragma unroll
  for (int i = 0; i < 8; i++){
    int s = by*128 + ty*8 + i;
    float adda[4], addb[4];
    if (MODE == 1){
      int t = t_act[s], o = op_idx[s];
      float4 ia = *(const float4*)&idW[t*512 + col0a];
      float4 ib = *(const float4*)&idW[t*512 + col0b];
      float4 oa = *(const float4*)&opWb[o*512 + col0a];
      float4 ob = *(const float4*)&opWb[o*512 + col0b];
      adda[0]=ia.x+oa.x; adda[1]=ia.y+oa.y; adda[2]=ia.z+oa.z; adda[3]=ia.w+oa.w;
      addb[0]=ib.x+ob.x; addb[1]=ib.y+ob.y; addb[2]=ib.z+ob.z; addb[3]=ib.w+ob.w;
    } else {
      float4 ba = *(const float4*)&bias[col0a];
      float4 bb = *(const float4*)&bias[col0b];
      adda[0]=ba.x; adda[1]=ba.y; adda[2]=ba.z; adda[3]=ba.w;
      addb[0]=bb.x; addb[1]=bb.y; addb[2]=bb.z; addb[3]=bb.w;
    }
    float4 va, vb;
    float* pa = &va.x; float* pb = &vb.x;
    #pragma unroll
    for (int j = 0; j < 4; j++){
      float v0 = acc[i][j]   + adda[j];
      float v1 = acc[i][j+4] + addb[j];
      if (MODE != 2){ v0 = fmaxf(v0, 0.f); v1 = fmaxf(v1, 0.f); }
      pa[j] = v0; pb[j] = v1;
    }
    *(float4*)(C + (size_t)s*Ncols + col0a) = va;
    *(float4*)(C + (size_t)s*Ncols + col0b) = vb;
  }
}

__global__ __launch_bounds__(256)
void k_routeF(const float* __restrict__ h2, const float* __restrict__ Wr1,
              const float* __restrict__ Wr2, const float* __restrict__ br2,
              const float* __restrict__ tidWb,
              const int* __restrict__ t_act, const int* __restrict__ aidx,
              const int* __restrict__ meta, const uint32_t* __restrict__ keys, int hop,
              float* __restrict__ states, int* __restrict__ tempers, int* __restrict__ done){
  __shared__ float Wr1s[256][32];
  __shared__ float h2s[8][512];
  __shared__ float l32[8][32];

  const int tid = threadIdx.x;
  const int s0 = blockIdx.x * 8;

  for (int i4 = tid; i4 < 8*128; i4 += 256){
    int sl = i4 >> 7, q = i4 & 127;
    *(float4*)&h2s[sl][q*4] = *(const float4*)&h2[(size_t)(s0+sl)*512 + q*4];
  }

  const int lane = tid & 63, w = tid >> 6;
  const int half = lane >> 5, col = lane & 31;
  const int sl = w*2 + half;
  const int s  = s0 + sl;
  const int t  = t_act[s];
  float acc = tidWb[t*32 + col];

  for (int kh = 0; kh < 2; kh++){
    __syncthreads();
    for (int idx = tid; idx < 256*32; idx += 256)
      Wr1s[idx >> 5][idx & 31] = Wr1[kh*8192 + idx];
    __syncthreads();
    const int kb = kh * 256;
    #pragma unroll 4
    for (int k4 = 0; k4 < 64; k4++){
      float4 hv = *(float4*)&h2s[sl][kb + k4*4];
      acc = fmaf(hv.x, Wr1s[k4*4+0][col], acc);
      acc = fmaf(hv.y, Wr1s[k4*4+1][col], acc);
      acc = fmaf(hv.z, Wr1s[k4*4+2][col], acc);
      acc = fmaf(hv.w, Wr1s[k4*4+3][col], acc);
    }
  }
  l32[sl][col] = fmaxf(acc, 0.f);
  __syncthreads();

  const uint32_t sk0 = keys[4 + 4*hop], sk1 = keys[5 + 4*hop];
  int smp[2];
  for (int pass = 0; pass < 2; pass++){
    const int psl = w*2 + pass;
    const int ps  = s0 + psl;
    const int c = lane;
    float lg = br2[c];
    #pragma unroll
    for (int k = 0; k < 32; k++) lg = fmaf(l32[psl][k], Wr2[k*65 + c], lg);
    float lg64 = br2[64];
    #pragma unroll
    for (int k = 0; k < 32; k++) lg64 = fmaf(l32[psl][k], Wr2[k*65 + 64], lg64);
    float m = lg;
    for (int off = 32; off; off >>= 1) m = fmaxf(m, __shfl_xor(m, off));
    m = fmaxf(m, lg64);
    float se = expf(lg - m);
    for (int off = 32; off; off >>= 1) se += __shfl_xor(se, off);
    se += expf(lg64 - m);
    float Lse = logf(se);
    float g = jgumbel(jbits32(sk0, sk1, (uint32_t)(65*ps + c)));
    float v = (lg - m) - Lse + g;
    int idx = c;
    for (int off = 32; off; off >>= 1){
      float ov = __shfl_xor(v, off);
      int   oi = __shfl_xor(idx, off);
      if (ov > v || (ov == v && oi < idx)){ v = ov; idx = oi; }
    }
    float g64 = jgumbel(jbits32(sk0, sk1, (uint32_t)(65*ps + 64)));
    float v64 = (lg64 - m) - Lse + g64;
    if (v64 > v) idx = 64;
    smp[pass] = idx;
  }

  const int mysmp = smp[half];
  const int p = aidx[s];
  const int w0v = meta[1];
  const bool allowed = (p != 0) || (s == w0v);
  if (allowed){
    const float4* src = (const float4*)&h2s[sl][0];
    float4* dst = (float4*)(states + (size_t)p*512);
    for (int q = col; q < 128; q += 32) dst[q] = src[q];
    if (col == 0){
      tempers[p] = (mysmp < 63) ? mysmp : 63;
      done[p]    = (mysmp == 64) ? 1 : 0;
    }
  }
}

__global__ __launch_bounds__(256)
void k_latentF(const float* __restrict__ states, float* __restrict__ out){
  int idx = blockIdx.x*256 + threadIdx.x;
  int b = idx >> 9, j = idx & 511;
  float s = 0.f;
  #pragma unroll
  for (int u = 0; u < 16; u++) s += states[(size_t)(b*16 + u)*512 + j];
  out[idx] = s * 0.0625f;
}

// ------------------------------- launch ------------------------------------
extern "C" void kernel_launch(void* const* d_in, const int* in_sizes, int n_in,
                              void* d_out, int out_size, void* d_ws, size_t ws_size,
                              hipStream_t stream) {
  (void)in_sizes; (void)n_in; (void)out_size;
  const float* x         = (const float*)d_in[0];
  const float* op_emb    = (const float*)d_in[1];
  const float* op_logits = (const float*)d_in[2];
  const float* id_embeds = (const float*)d_in[3];
  const float* W1        = (const float*)d_in[4];
  const float* b1        = (const float*)d_in[5];
  const float* W2        = (const float*)d_in[6];
  const float* b2        = (const float*)d_in[7];
  const float* Wr1       = (const float*)d_in[8];
  const float* br1       = (const float*)d_in[9];
  const float* Wr2       = (const float*)d_in[10];
  const float* br2       = (const float*)d_in[11];
  const float* Wp        = (const float*)d_in[12];
  const float* bp        = (const float*)d_in[13];
  const float* tid_emb   = (const float*)d_in[14];
  const int*   seed      = (const int*)d_in[15];
  float* out = (float*)d_out;

  char* w = (char*)d_ws;
  uint32_t* keys = (uint32_t*)w;                 // @0
  float* logp3   = (float*)(w + 256);
  int*   meta    = (int*)(w + 512);
  int*   tempers = (int*)(w + 4096);
  int*   done    = tempers + NPATCH;
  int*   t_act   = done + NPATCH;
  int*   op_idx  = t_act + NPATCH;
  int*   aidx    = op_idx + NPATCH;
  float* idW     = (float*)(aidx + NPATCH);
  float* opWb    = idW + 64*512;
  float* tidWb   = opWb + 3*512;                 // ends < 1 MB

  const size_t SPh = (size_t)NPATCH*512;
  u16* W1T     = (u16*)(w + (1u<<20));           // 2 planes 512x512
  u16* W2T     = W1T + (size_t)2*512*512;        // 2 planes 512x512
  u16* Wr1P    = W2T + (size_t)2*512*512;        // 2 planes 32x512
  u16* WpT     = Wr1P + (size_t)2*32*512;        // 1 plane 8192x512
  u16* latP    = WpT + (size_t)8192*512;         // 1 plane 2048x512
  u16* statesP = latP + (size_t)2048*512;        // 2 planes
  u16* h1P     = statesP + 2*SPh;                // 2 planes
  float* l32g  = (float*)(h1P + 2*SPh);          // 32768 x 32 fp32
  const size_t NEED = (size_t)((char*)(l32g + (size_t)NPATCH*32) - w);

  k_keys<<<1, 64, 0, stream>>>(seed, op_logits, keys, logp3);
  k_init<<<NPATCH/256, 256, 0, stream>>>(keys, tempers, done);
  k_precomp<<<68, 256, 0, stream>>>(id_embeds, op_emb, tid_emb, W1, b1, Wr1, br1,
                                    idW, opWb, tidWb);

  if (ws_size >= NEED){
    // ---------------- fp16x2 MFMA path ----------------
    k_splitW<<<4624, 256, 0, stream>>>(W1, W2, Wp, Wr1, W1T, W2T, WpT, Wr1P);
    k_xsplit<<<(NPATCH*512/4)/256, 256, 0, stream>>>(x, statesP);

    for (int hop = 0; hop < NHOP; hop++){
      k_scan<<<1, 1024, 0, stream>>>(done, aidx, meta);
      k_gather<<<NPATCH/256, 256, 0, stream>>>(aidx, tempers, keys, logp3, hop, t_act, op_idx);
      k_mgemm<1,2><<<dim3(4, NPATCH/128), 256, 0, stream>>>(
          statesP, W1T, nullptr, h1P, aidx, nullptr, idW, opWb, t_act, op_idx, meta,
          512, SPh, (size_t)512*512, SPh);
      k_mgemm<3,2><<<dim3(4, NPATCH/128), 256, 0, stream>>>(
          h1P, W2T, nullptr, statesP, aidx, b2, nullptr, nullptr, nullptr, nullptr, meta,
          512, SPh, (size_t)512*512, SPh);
      k_routemm<<<NPATCH/64, 256, 0, stream>>>(statesP, Wr1P, aidx, t_act, tidWb, l32g);
      k_sample<<<NPATCH/8, 256, 0, stream>>>(l32g, Wr2, br2, aidx, meta, keys, hop,
                                             tempers, done);
    }

    k_latent2<<<(2048*512)/256, 256, 0, stream>>>(statesP, out, latP);
    k_mgemm<2,1><<<dim3(64, 16), 256, 0, stream>>>(
        latP, WpT, out + 2048*512, nullptr, nullptr, bp, nullptr, nullptr, nullptr, nullptr,
        nullptr, 8192, (size_t)2048*512, (size_t)8192*512, 0);
  } else {
    // ---------------- R1 fp32 fallback ----------------
    const size_t BIG0 = 2u<<20;
    const size_t SB   = (size_t)NPATCH * 512 * sizeof(float);
    float *states, *h1, *h2;
    bool copy_states;
    if (ws_size >= BIG0 + 3*SB){
      states = (float*)(w + BIG0);
      h1     = (float*)(w + BIG0 + SB);
      h2     = (float*)(w + BIG0 + 2*SB);
      copy_states = true;
    } else {
      states = (float*)d_in[0];
      h1     = (float*)(w + BIG0);
      h2     = (float*)(w + BIG0 + SB);
      copy_states = false;
    }
    if (copy_states)
      hipMemcpyAsync(states, x, SB, hipMemcpyDeviceToDevice, stream);

    for (int hop = 0; hop < NHOP; hop++){
      k_scan<<<1, 1024, 0, stream>>>(done, aidx, meta);
      k_gather<<<NPATCH/256, 256, 0, stream>>>(aidx, tempers, keys, logp3, hop, t_act, op_idx);
      k_gemmF<1><<<dim3(4, NPATCH/128), 256, 0, stream>>>(states, W1, h1, 512,
                                      aidx, nullptr, idW, opWb, t_act, op_idx);
      k_gemmF<0><<<dim3(4, NPATCH/128), 256, 0, stream>>>(h1, W2, h2, 512,
                                      nullptr, b2, nullptr, nullptr, nullptr, nullptr);
      k_routeF<<<NPATCH/8, 256, 0, stream>>>(h2, Wr1, Wr2, br2, tidWb, t_act, aidx,
                                      meta, keys, hop, states, tempers, done);
    }

    k_latentF<<<(2048*512)/256, 256, 0, stream>>>(states, out);
    k_gemmF<2><<<dim3(8192/128, 2048/128), 256, 0, stream>>>(out, Wp, out + 2048*512, 8192,
                                      nullptr, bp, nullptr, nullptr, nullptr, nullptr);
  }
}